// Round 4
// baseline (361.574 us; speedup 1.0000x reference)
//
#include <hip/hip_runtime.h>
#include <cstdint>

// ---------- sizes ----------
#define BT_ROWS 4096      // B*T
#define DM      1024
#define DFF     2730
#define DFFP    2816      // padded to /128
#define TSEQ    2048

typedef float  f32x4  __attribute__((ext_vector_type(4)));
typedef __bf16 bf16x8 __attribute__((ext_vector_type(8)));

typedef __attribute__((address_space(1))) const unsigned int as1_uint;
typedef __attribute__((address_space(3))) unsigned int       as3_uint;

__device__ __forceinline__ unsigned short f2bf(float f) {
  union { float f; unsigned int u; } v; v.f = f;
  unsigned int u = v.u;
  return (unsigned short)((u + 0x7fffu + ((u >> 16) & 1u)) >> 16);  // RNE
}
__device__ __forceinline__ float bf2f(unsigned int b) {
  union { unsigned int u; float f; } v; v.u = b << 16;
  return v.f;
}

__device__ __forceinline__ void async_cp16(const void* g, void* l) {
  // 16B-wide global->LDS DMA; LDS dest is wave-uniform base + lane*16
  __builtin_amdgcn_global_load_lds((as1_uint*)(uintptr_t)g, (as3_uint*)(uintptr_t)l, 16, 0, 0);
}

// ---------- weight convert (+optional zero pad) ----------
__global__ void cvt_pad_kernel(const float* __restrict__ src, unsigned short* __restrict__ dst,
                               int Rs, int Cs, long total, int Cd) {
  long idx = (long)blockIdx.x * 256 + threadIdx.x;
  if (idx >= total) return;
  int r = (int)(idx / Cd), c = (int)(idx % Cd);
  float v = (r < Rs && c < Cs) ? src[(long)r * Cs + c] : 0.f;
  dst[idx] = f2bf(v);
}

// ---------- RMSNorm (fp32 in -> bf16 out), one block per row ----------
__global__ void rmsnorm_kernel(const float* __restrict__ x, const float* __restrict__ g,
                               unsigned short* __restrict__ out) {
  const int row = blockIdx.x, tid = threadIdx.x;
  const float4 xv = reinterpret_cast<const float4*>(x + (long)row * DM)[tid];
  float ss = xv.x * xv.x + xv.y * xv.y + xv.z * xv.z + xv.w * xv.w;
#pragma unroll
  for (int o = 32; o > 0; o >>= 1) ss += __shfl_xor(ss, o);
  __shared__ float wsum[4];
  if ((tid & 63) == 0) wsum[tid >> 6] = ss;
  __syncthreads();
  const float inv = rsqrtf((wsum[0] + wsum[1] + wsum[2] + wsum[3]) * (1.f / DM) + 1e-5f);
  const float4 gv = reinterpret_cast<const float4*>(g)[tid];
  ushort4 o4;
  o4.x = f2bf(xv.x * inv * gv.x);
  o4.y = f2bf(xv.y * inv * gv.y);
  o4.z = f2bf(xv.z * inv * gv.z);
  o4.w = f2bf(xv.w * inv * gv.w);
  reinterpret_cast<ushort4*>(out + (long)row * DM)[tid] = o4;
}

// ---------- RoPE cos/sin table ----------
__global__ void trig_kernel(const int* __restrict__ pos, float* __restrict__ ct, float* __restrict__ st) {
  int idx = blockIdx.x * 256 + threadIdx.x;
  if (idx >= BT_ROWS * 32) return;
  int r = idx >> 5, i = idx & 31;
  float f = powf(10000.f, -(float)(2 * i) * (1.f / 64.f));
  float ang = (float)pos[r] * f;
  float sv, cv;
  sincosf(ang, &sv, &cv);
  ct[idx] = cv; st[idx] = sv;
}

// ---------- RoPE applied in-place to Q,K halves of QK buf (bf16, ld 2048) ----------
__global__ void rope_kernel(unsigned short* __restrict__ QK,
                            const float* __restrict__ ct, const float* __restrict__ st) {
  int idx = blockIdx.x * 256 + threadIdx.x;  // over 4096*512 (row, head*pair)
  if (idx >= BT_ROWS * 512) return;
  int r = idx >> 9, p = idx & 511;
  int h = p >> 5, i = p & 31;
  float c = ct[r * 32 + i], s = st[r * 32 + i];
  unsigned int* base = reinterpret_cast<unsigned int*>(QK + (long)r * 2048 + h * 64 + 2 * i);
  unsigned int q01 = base[0];
  float x0 = bf2f(q01 & 0xffffu), x1 = bf2f(q01 >> 16);
  base[0] = (unsigned int)f2bf(c * x0 - s * x1) | ((unsigned int)f2bf(s * x0 + c * x1) << 16);
  unsigned int k01 = base[512];  // +1024 shorts = K block
  float y0 = bf2f(k01 & 0xffffu), y1 = bf2f(k01 >> 16);
  base[512] = (unsigned int)f2bf(c * y0 - s * y1) | ((unsigned int)f2bf(s * y0 + c * y1) << 16);
}

// ---------- GEMM: C[M,N] = A[M,K] * B[N,K]^T  (bf16 in, fp32 acc) ----------
// EPI 0: bf16 [row][col] store; EPI 1: fp32 store of acc + resid
template <int EPI>
__global__ __launch_bounds__(256) void gemm_bt(
    const unsigned short* __restrict__ A, const unsigned short* __restrict__ B,
    void* __restrict__ C, const float* __restrict__ resid,
    int M, int N, int K, int ldc) {
  __shared__ unsigned short As[128 * 32];
  __shared__ unsigned short Bs[128 * 32];
  const int tid = threadIdx.x;
  const int wid = tid >> 6;
  const int lane = tid & 63;
  const long rowBase = (long)blockIdx.y * 128;
  const long colBase = (long)blockIdx.x * 128;
  const int wm = (wid >> 1) * 64;
  const int wn = (wid & 1) * 64;
  const int l4 = lane >> 2;        // staging: row within 16-row chunk
  const int c8 = (lane & 3) * 8;   // staging: col (8 bf16 = 16B)
  const int fr = lane & 15;        // fragment row
  const int fg = lane >> 4;        // fragment k-group

  const f32x4 z4 = {0.f, 0.f, 0.f, 0.f};
  f32x4 acc[4][4];
#pragma unroll
  for (int m = 0; m < 4; ++m)
#pragma unroll
    for (int n = 0; n < 4; ++n) acc[m][n] = z4;

  const int nkt = K >> 5;
  for (int kt = 0; kt < nkt; ++kt) {
    if (kt) __syncthreads();  // previous compute done before LDS overwrite
    const long kOff = (long)kt * 32 + c8;
#pragma unroll
    for (int c = 0; c < 2; ++c) {
      const int chunk = c * 4 + wid;  // wave-uniform LDS base
      async_cp16(A + (rowBase + chunk * 16 + l4) * K + kOff, &As[chunk * 512]);
      async_cp16(B + (colBase + chunk * 16 + l4) * K + kOff, &Bs[chunk * 512]);
    }
    __syncthreads();  // compiler drains vmcnt(0) before s_barrier -> LDS ready
    bf16x8 af[4], bfr[4];
#pragma unroll
    for (int m = 0; m < 4; ++m)
      af[m] = *reinterpret_cast<const bf16x8*>(&As[(wm + m * 16 + fr) * 32 + fg * 8]);
#pragma unroll
    for (int n = 0; n < 4; ++n)
      bfr[n] = *reinterpret_cast<const bf16x8*>(&Bs[(wn + n * 16 + fr) * 32 + fg * 8]);
#pragma unroll
    for (int m = 0; m < 4; ++m)
#pragma unroll
      for (int n = 0; n < 4; ++n)
        acc[m][n] = __builtin_amdgcn_mfma_f32_16x16x32_bf16(af[m], bfr[n], acc[m][n], 0, 0, 0);
  }

  const int erow = fg * 4;  // C: col = lane&15, row = (lane>>4)*4 + reg
  if (EPI == 0) {
    unsigned short* Cp = (unsigned short*)C;
#pragma unroll
    for (int m = 0; m < 4; ++m) {
      const long r0 = rowBase + wm + m * 16 + erow;
#pragma unroll
      for (int n = 0; n < 4; ++n) {
        const long col = colBase + wn + n * 16 + fr;
#pragma unroll
        for (int r = 0; r < 4; ++r) Cp[(r0 + r) * ldc + col] = f2bf(acc[m][n][r]);
      }
    }
  } else {
    float* Cf = (float*)C;
#pragma unroll
    for (int m = 0; m < 4; ++m) {
      const long r0 = rowBase + wm + m * 16 + erow;
#pragma unroll
      for (int n = 0; n < 4; ++n) {
        const long col = colBase + wn + n * 16 + fr;
#pragma unroll
        for (int r = 0; r < 4; ++r) {
          const long o = (r0 + r) * ldc + col;
          Cf[o] = acc[m][n][r] + resid[o];
        }
      }
    }
  }
}

// ---------- flash attention, causal, 16 heads x d_k=64 ----------
// S' = K*Q^T (swapped); K-row permutation + XOR chunk swizzle are baked into
// the per-lane GLOBAL source addresses of global_load_lds (LDS stays linear,
// m173 pattern). ds_read_b128 fragment reads are conflict-free and use only
// immediate offsets off 2 per-lane bases. V^T read from global (L2-resident).
// Block = 4 waves x 16 q-rows, KVBLK=64, double-buffered, 1 barrier/tile.
__global__ __launch_bounds__(256) void attn_kernel(
    const unsigned short* __restrict__ QK, const unsigned short* __restrict__ Vt,
    unsigned short* __restrict__ O) {
  __shared__ unsigned short Ks[2 * 64 * 64];
  const int bh = blockIdx.x;
  const int b = bh >> 4, h = bh & 15;
  const int tid = threadIdx.x;
  const int wid = tid >> 6, lane = tid & 63;
  const int qblk = 31 - blockIdx.y;              // longest-first dispatch
  const int qbase = qblk * 64 + wid * 16;
  const int fr = lane & 15, g = lane >> 4;
  const long rowb = (long)b * TSEQ;
  const int hoff = h * 64;
  const float C2 = 0.18033688011112042f;         // 0.125 * log2(e)

  // Q fragments
  const unsigned short* qrow = QK + (rowb + qbase + fr) * 2048 + hoff + g * 8;
  const bf16x8 qb0 = *reinterpret_cast<const bf16x8*>(qrow);
  const bf16x8 qb1 = *reinterpret_cast<const bf16x8*>(qrow + 32);

  // K staging: per-lane pre-permuted, pre-swizzled global sources
  const unsigned short* Kg = QK + rowb * 2048 + 1024 + hoff;
  const unsigned short* gk0;
  const unsigned short* gk1;
  {
    const int c = lane & 7;
    int r = wid * 8 + (lane >> 3);               // issue 0: rows 0..31
    int kgr = 8 * ((r & 15) >> 2) + (r & 3) + 4 * ((r >> 4) & 1);
    gk0 = Kg + (long)kgr * 2048 + ((c ^ (r & 7)) * 8);
    r += 32;                                     // issue 1: rows 32..63
    kgr = 32 + 8 * ((r & 15) >> 2) + (r & 3) + 4 * ((r >> 4) & 1);
    gk1 = Kg + (long)kgr * 2048 + ((c ^ (r & 7)) * 8);
  }
  char* ldsB = (char*)Ks;
  const int cA = g ^ (fr & 7);                   // XOR-swizzled read chunks
  const int baseA = fr * 128 + cA * 16;          // d 8g..8g+7
  const int baseB = fr * 128 + (cA ^ 4) * 16;    // d 32+8g..

  // V^T pointers: Vt[(h*64+d)][b*2048 + t]
  const unsigned short* pV0 = Vt + (long)(hoff + fr) * 4096 + rowb + g * 8;
  const unsigned short* pV1 = pV0 + 16 * 4096;
  const unsigned short* pV2 = pV0 + 32 * 4096;
  const unsigned short* pV3 = pV0 + 48 * 4096;

  const f32x4 z4 = {0.f, 0.f, 0.f, 0.f};
  f32x4 acc[4];
#pragma unroll
  for (int d = 0; d < 4; ++d) acc[d] = z4;
  float mrun = -1e30f, lrun = 0.f;
  const int qg = qbase + fr;
  const int nkt = qblk + 1;

  // prologue: stage tile 0 into buf 0
  async_cp16(gk0, ldsB + wid * 1024);
  async_cp16(gk1, ldsB + 4096 + wid * 1024);
  gk0 += 64 * 2048; gk1 += 64 * 2048;

  for (int kt = 0; kt < nkt; ++kt) {
    __syncthreads();                             // drains vmcnt -> cur buf ready
    const char* cur = ldsB + (kt & 1) * 8192;
    if (kt + 1 < nkt) {                          // prefetch next tile (in flight
      char* nxt = ldsB + ((kt + 1) & 1) * 8192;  //  until next barrier)
      async_cp16(gk0, nxt + wid * 1024);
      async_cp16(gk1, nxt + 4096 + wid * 1024);
      gk0 += 64 * 2048; gk1 += 64 * 2048;
    }
    const int kbase = kt * 64;
    // V fragments early (hide under QK^T + softmax)
    bf16x8 vf[4][2];
    vf[0][0] = *(const bf16x8*)pV0; vf[0][1] = *(const bf16x8*)(pV0 + 32); pV0 += 64;
    vf[1][0] = *(const bf16x8*)pV1; vf[1][1] = *(const bf16x8*)(pV1 + 32); pV1 += 64;
    vf[2][0] = *(const bf16x8*)pV2; vf[2][1] = *(const bf16x8*)(pV2 + 32); pV2 += 64;
    vf[3][0] = *(const bf16x8*)pV3; vf[3][1] = *(const bf16x8*)(pV3 + 32); pV3 += 64;

    // QK^T: 2 k-halves x 2 row-groups x 2 d-halves
    f32x4 s1[2], s2[2];
#pragma unroll
    for (int ks = 0; ks < 2; ++ks) {
      const int o = ks * 4096;
      const bf16x8 a0 = *(const bf16x8*)(cur + baseA + o);
      const bf16x8 a1 = *(const bf16x8*)(cur + baseB + o);
      const bf16x8 c0 = *(const bf16x8*)(cur + baseA + o + 2048);
      const bf16x8 c1 = *(const bf16x8*)(cur + baseB + o + 2048);
      f32x4 t1 = z4, t2 = z4;
      t1 = __builtin_amdgcn_mfma_f32_16x16x32_bf16(a0, qb0, t1, 0, 0, 0);
      t1 = __builtin_amdgcn_mfma_f32_16x16x32_bf16(a1, qb1, t1, 0, 0, 0);
      t2 = __builtin_amdgcn_mfma_f32_16x16x32_bf16(c0, qb0, t2, 0, 0, 0);
      t2 = __builtin_amdgcn_mfma_f32_16x16x32_bf16(c1, qb1, t2, 0, 0, 0);
      s1[ks] = t1; s2[ks] = t2;
    }

    // lane's 16 raw scores: k = kbase + ks*32 + 8g + {j | 4+j}
    float sc[16];
    if (kt + 1 < nkt) {  // fully causal-visible tile: no mask
#pragma unroll
      for (int ks = 0; ks < 2; ++ks)
#pragma unroll
        for (int j = 0; j < 4; ++j) {
          sc[ks * 8 + j] = s1[ks][j];
          sc[ks * 8 + 4 + j] = s2[ks][j];
        }
    } else {
      const int kb8 = kbase + 8 * g;
#pragma unroll
      for (int ks = 0; ks < 2; ++ks)
#pragma unroll
        for (int j = 0; j < 4; ++j) {
          sc[ks * 8 + j]     = (kb8 + ks * 32 + j     <= qg) ? s1[ks][j] : -1e30f;
          sc[ks * 8 + 4 + j] = (kb8 + ks * 32 + 4 + j <= qg) ? s2[ks][j] : -1e30f;
        }
    }
    // max via v_max3 tree
    const float t0 = fmaxf(fmaxf(sc[0], sc[1]), sc[2]);
    const float t1 = fmaxf(fmaxf(sc[3], sc[4]), sc[5]);
    const float t2 = fmaxf(fmaxf(sc[6], sc[7]), sc[8]);
    const float t3 = fmaxf(fmaxf(sc[9], sc[10]), sc[11]);
    const float t4 = fmaxf(fmaxf(sc[12], sc[13]), sc[14]);
    float tmax = fmaxf(fmaxf(fmaxf(t0, t1), t2), fmaxf(fmaxf(t3, t4), sc[15]));
    tmax = fmaxf(tmax, __shfl_xor(tmax, 16));
    tmax = fmaxf(tmax, __shfl_xor(tmax, 32));
    if (__any(tmax > mrun)) {                    // T13 exact: skip when alpha==1
      const float mnew = fmaxf(mrun, tmax);
      const float alpha = exp2f((mrun - mnew) * C2);
#pragma unroll
      for (int db = 0; db < 4; ++db)
#pragma unroll
        for (int r = 0; r < 4; ++r) acc[db][r] *= alpha;
      lrun *= alpha;
      mrun = mnew;
    }
    const float m2 = mrun * C2;
    bf16x8 pbv[2];
    float psum = 0.f;
#pragma unroll
    for (int ks = 0; ks < 2; ++ks)
#pragma unroll
      for (int j = 0; j < 8; ++j) {
        const float p = exp2f(fmaf(sc[ks * 8 + j], C2, -m2));
        psum += p;
        pbv[ks][j] = (__bf16)p;                  // compiler packs v_cvt_pk_bf16_f32
      }
    psum += __shfl_xor(psum, 16);
    psum += __shfl_xor(psum, 32);
    lrun += psum;

    // PV: acc[db] += V^T-frag * P'-frag
    acc[0] = __builtin_amdgcn_mfma_f32_16x16x32_bf16(vf[0][0], pbv[0], acc[0], 0, 0, 0);
    acc[0] = __builtin_amdgcn_mfma_f32_16x16x32_bf16(vf[0][1], pbv[1], acc[0], 0, 0, 0);
    acc[1] = __builtin_amdgcn_mfma_f32_16x16x32_bf16(vf[1][0], pbv[0], acc[1], 0, 0, 0);
    acc[1] = __builtin_amdgcn_mfma_f32_16x16x32_bf16(vf[1][1], pbv[1], acc[1], 0, 0, 0);
    acc[2] = __builtin_amdgcn_mfma_f32_16x16x32_bf16(vf[2][0], pbv[0], acc[2], 0, 0, 0);
    acc[2] = __builtin_amdgcn_mfma_f32_16x16x32_bf16(vf[2][1], pbv[1], acc[2], 0, 0, 0);
    acc[3] = __builtin_amdgcn_mfma_f32_16x16x32_bf16(vf[3][0], pbv[0], acc[3], 0, 0, 0);
    acc[3] = __builtin_amdgcn_mfma_f32_16x16x32_bf16(vf[3][1], pbv[1], acc[3], 0, 0, 0);
  }

  const float inv = 1.f / lrun;
  unsigned short* orow = O + (rowb + qbase + fr) * DM + hoff;
#pragma unroll
  for (int db = 0; db < 4; ++db) {
    uint2 pk;
    pk.x = (unsigned int)f2bf(acc[db][0] * inv) | ((unsigned int)f2bf(acc[db][1] * inv) << 16);
    pk.y = (unsigned int)f2bf(acc[db][2] * inv) | ((unsigned int)f2bf(acc[db][3] * inv) << 16);
    *reinterpret_cast<uint2*>(orow + db * 16 + g * 4) = pk;
  }
}

// ---------- SwiGLU: s = U*sigmoid(U)*G, zero the padded cols ----------
__global__ void swiglu_kernel(const unsigned short* __restrict__ UG, unsigned short* __restrict__ S) {
  int idx = blockIdx.x * 256 + threadIdx.x;  // 4096 * (2816/8)
  if (idx >= BT_ROWS * (DFFP / 8)) return;
  int r = idx / (DFFP / 8);
  int c8 = (idx % (DFFP / 8)) * 8;
  const unsigned short* u8 = UG + (long)r * (2 * DFFP) + c8;
  const uint4 uv = *reinterpret_cast<const uint4*>(u8);
  const uint4 gv = *reinterpret_cast<const uint4*>(u8 + DFFP);
  float uu[8] = {bf2f(uv.x & 0xffffu), bf2f(uv.x >> 16), bf2f(uv.y & 0xffffu), bf2f(uv.y >> 16),
                 bf2f(uv.z & 0xffffu), bf2f(uv.z >> 16), bf2f(uv.w & 0xffffu), bf2f(uv.w >> 16)};
  float gg[8] = {bf2f(gv.x & 0xffffu), bf2f(gv.x >> 16), bf2f(gv.y & 0xffffu), bf2f(gv.y >> 16),
                 bf2f(gv.z & 0xffffu), bf2f(gv.z >> 16), bf2f(gv.w & 0xffffu), bf2f(gv.w >> 16)};
  unsigned short ov[8];
#pragma unroll
  for (int j = 0; j < 8; ++j) {
    float v = (c8 + j < DFF) ? uu[j] * gg[j] / (1.f + __expf(-uu[j])) : 0.f;
    ov[j] = f2bf(v);
  }
  ushort4* dst = reinterpret_cast<ushort4*>(S + (long)r * DFFP + c8);
  dst[0] = make_ushort4(ov[0], ov[1], ov[2], ov[3]);
  dst[1] = make_ushort4(ov[4], ov[5], ov[6], ov[7]);
}

// ---------- workspace layout (123.2 MB, lifetime-reused) ----------
static constexpr size_t OFF_WQKV = 0;          // [3072,1024] bf16
static constexpr size_t OFF_WO   = 6291456;    // [1024,1024] bf16
static constexpr size_t OFF_W13  = 8388608;    // [5632,1024] bf16 (W1 pad | W3 pad)
static constexpr size_t OFF_W2   = 19922944;   // [1024,2816] bf16
static constexpr size_t OFF_H    = 25690112;   // [4096,1024] bf16
static constexpr size_t OFF_X2   = 34078720;   // [4096,1024] f32
static constexpr size_t OFF_CT   = 50855936;   // [4096,32] f32
static constexpr size_t OFF_ST   = 51380224;   // [4096,32] f32
static constexpr size_t OFF_QK   = 51904512;   // [4096,2048] bf16 (later: S [4096,2816])
static constexpr size_t OFF_VT   = 68681728;   // [1024,(h,d)][4096 (b,t)] bf16, 8MB
static constexpr size_t OFF_HO   = 77070336;   // [4096,1024] bf16 (later: UG [4096,5632])

extern "C" void kernel_launch(void* const* d_in, const int* in_sizes, int n_in,
                              void* d_out, int out_size, void* d_ws, size_t ws_size,
                              hipStream_t stream) {
  const float* x  = (const float*)d_in[0];
  const int* tpos = (const int*)d_in[1];
  const float* WQ = (const float*)d_in[2];
  const float* WK = (const float*)d_in[3];
  const float* WV = (const float*)d_in[4];
  const float* WO = (const float*)d_in[5];
  const float* W1 = (const float*)d_in[6];
  const float* W2 = (const float*)d_in[7];
  const float* W3 = (const float*)d_in[8];
  const float* g1 = (const float*)d_in[9];
  const float* g2 = (const float*)d_in[10];
  float* out = (float*)d_out;

  char* ws = (char*)d_ws;
  unsigned short* Wqkv = (unsigned short*)(ws + OFF_WQKV);
  unsigned short* Wo   = (unsigned short*)(ws + OFF_WO);
  unsigned short* W13  = (unsigned short*)(ws + OFF_W13);
  unsigned short* W2p  = (unsigned short*)(ws + OFF_W2);
  unsigned short* hbuf = (unsigned short*)(ws + OFF_H);
  float* x2            = (float*)(ws + OFF_X2);
  float* ct            = (float*)(ws + OFF_CT);
  float* st            = (float*)(ws + OFF_ST);
  unsigned short* QKb  = (unsigned short*)(ws + OFF_QK);
  unsigned short* Sbuf = (unsigned short*)(ws + OFF_QK);   // reuse after attn
  unsigned short* Vtb  = (unsigned short*)(ws + OFF_VT);
  unsigned short* Ho   = (unsigned short*)(ws + OFF_HO);
  unsigned short* UG   = (unsigned short*)(ws + OFF_HO);   // reuse after O-proj

  // weights -> bf16 (packed, padded)
  auto cvt = [&](const float* s, unsigned short* d, int Rs, int Cs, int Rd, int Cd) {
    long tot = (long)Rd * Cd;
    cvt_pad_kernel<<<(int)((tot + 255) / 256), 256, 0, stream>>>(s, d, Rs, Cs, tot, Cd);
  };
  cvt(WQ, Wqkv,              1024, 1024, 1024, 1024);
  cvt(WK, Wqkv + 1024 * 1024,1024, 1024, 1024, 1024);
  cvt(WV, Wqkv + 2048 * 1024,1024, 1024, 1024, 1024);
  cvt(WO, Wo,                1024, 1024, 1024, 1024);
  cvt(W1, W13,               DFF,  1024, DFFP, 1024);
  cvt(W3, W13 + DFFP * 1024, DFF,  1024, DFFP, 1024);
  cvt(W2, W2p,               1024, DFF,  1024, DFFP);

  // attention sublayer
  rmsnorm_kernel<<<BT_ROWS, 256, 0, stream>>>(x, g1, hbuf);
  trig_kernel<<<(BT_ROWS * 32) / 256, 256, 0, stream>>>(tpos, ct, st);
  gemm_bt<0><<<dim3(16, 32), 256, 0, stream>>>(hbuf, Wqkv, QKb, nullptr, BT_ROWS, 2048, 1024, 2048);
  // Vt = Wv * h^T : coalesced V^T with the standard epilogue
  gemm_bt<0><<<dim3(32, 8), 256, 0, stream>>>(Wqkv + 2048 * 1024, hbuf, Vtb, nullptr, 1024, BT_ROWS, 1024, BT_ROWS);
  rope_kernel<<<(BT_ROWS * 512) / 256, 256, 0, stream>>>(QKb, ct, st);
  attn_kernel<<<dim3(32, 32), 256, 0, stream>>>(QKb, Vtb, Ho);
  gemm_bt<1><<<dim3(8, 32), 256, 0, stream>>>(Ho, Wo, x2, x, BT_ROWS, 1024, 1024, 1024);

  // FFN sublayer
  rmsnorm_kernel<<<BT_ROWS, 256, 0, stream>>>(x2, g2, hbuf);
  gemm_bt<0><<<dim3(44, 32), 256, 0, stream>>>(hbuf, W13, UG, nullptr, BT_ROWS, 2 * DFFP, 1024, 2 * DFFP);
  swiglu_kernel<<<(BT_ROWS * (DFFP / 8) + 255) / 256, 256, 0, stream>>>(UG, Sbuf);
  gemm_bt<1><<<dim3(8, 32), 256, 0, stream>>>(Sbuf, W2p, out, x2, BT_ROWS, 1024, DFFP, 1024);
}

// Round 5
// 328.362 us; speedup vs baseline: 1.1011x; 1.1011x over previous
//
#include <hip/hip_runtime.h>
#include <cstdint>

// ---------- sizes ----------
#define BT_ROWS 4096      // B*T
#define DM      1024
#define DFF     2730
#define DFFP    2816      // padded to /128
#define TSEQ    2048

typedef float  f32x4  __attribute__((ext_vector_type(4)));
typedef __bf16 bf16x8 __attribute__((ext_vector_type(8)));

typedef __attribute__((address_space(1))) const unsigned int as1_uint;
typedef __attribute__((address_space(3))) unsigned int       as3_uint;

__device__ __forceinline__ unsigned short f2bf(float f) {
  union { float f; unsigned int u; } v; v.f = f;
  unsigned int u = v.u;
  return (unsigned short)((u + 0x7fffu + ((u >> 16) & 1u)) >> 16);  // RNE
}
__device__ __forceinline__ float bf2f(unsigned int b) {
  union { unsigned int u; float f; } v; v.u = b << 16;
  return v.f;
}

__device__ __forceinline__ void async_cp16(const void* g, void* l) {
  // 16B-wide global->LDS DMA; LDS dest is wave-uniform base + lane*16
  __builtin_amdgcn_global_load_lds((as1_uint*)(uintptr_t)g, (as3_uint*)(uintptr_t)l, 16, 0, 0);
}

// ---------- weight convert (+zero pad, +row stride/offset for interleaving) ----------
__global__ void cvt_pad_kernel(const float* __restrict__ src, unsigned short* __restrict__ dst,
                               int Rs, int Cs, long total, int Cd, int RS, int RO) {
  long idx = (long)blockIdx.x * 256 + threadIdx.x;
  if (idx >= total) return;
  int r = (int)(idx / Cd), c = (int)(idx % Cd);
  float v = (r < Rs && c < Cs) ? src[(long)r * Cs + c] : 0.f;
  dst[((long)r * RS + RO) * Cd + c] = f2bf(v);
}

// ---------- RMSNorm (fp32 in -> bf16 out), one block per row ----------
__global__ void rmsnorm_kernel(const float* __restrict__ x, const float* __restrict__ g,
                               unsigned short* __restrict__ out) {
  const int row = blockIdx.x, tid = threadIdx.x;
  const float4 xv = reinterpret_cast<const float4*>(x + (long)row * DM)[tid];
  float ss = xv.x * xv.x + xv.y * xv.y + xv.z * xv.z + xv.w * xv.w;
#pragma unroll
  for (int o = 32; o > 0; o >>= 1) ss += __shfl_xor(ss, o);
  __shared__ float wsum[4];
  if ((tid & 63) == 0) wsum[tid >> 6] = ss;
  __syncthreads();
  const float inv = rsqrtf((wsum[0] + wsum[1] + wsum[2] + wsum[3]) * (1.f / DM) + 1e-5f);
  const float4 gv = reinterpret_cast<const float4*>(g)[tid];
  ushort4 o4;
  o4.x = f2bf(xv.x * inv * gv.x);
  o4.y = f2bf(xv.y * inv * gv.y);
  o4.z = f2bf(xv.z * inv * gv.z);
  o4.w = f2bf(xv.w * inv * gv.w);
  reinterpret_cast<ushort4*>(out + (long)row * DM)[tid] = o4;
}

// ---------- RoPE cos/sin table ----------
__global__ void trig_kernel(const int* __restrict__ pos, float* __restrict__ ct, float* __restrict__ st) {
  int idx = blockIdx.x * 256 + threadIdx.x;
  if (idx >= BT_ROWS * 32) return;
  int r = idx >> 5, i = idx & 31;
  float f = powf(10000.f, -(float)(2 * i) * (1.f / 64.f));
  float ang = (float)pos[r] * f;
  float sv, cv;
  sincosf(ang, &sv, &cv);
  ct[idx] = cv; st[idx] = sv;
}

// ---------- RoPE applied in-place to Q,K halves of QK buf (bf16, ld 2048) ----------
__global__ void rope_kernel(unsigned short* __restrict__ QK,
                            const float* __restrict__ ct, const float* __restrict__ st) {
  int idx = blockIdx.x * 256 + threadIdx.x;  // over 4096*512 (row, head*pair)
  if (idx >= BT_ROWS * 512) return;
  int r = idx >> 9, p = idx & 511;
  int h = p >> 5, i = p & 31;
  float c = ct[r * 32 + i], s = st[r * 32 + i];
  unsigned int* base = reinterpret_cast<unsigned int*>(QK + (long)r * 2048 + h * 64 + 2 * i);
  unsigned int q01 = base[0];
  float x0 = bf2f(q01 & 0xffffu), x1 = bf2f(q01 >> 16);
  base[0] = (unsigned int)f2bf(c * x0 - s * x1) | ((unsigned int)f2bf(s * x0 + c * x1) << 16);
  unsigned int k01 = base[512];  // +1024 shorts = K block
  float y0 = bf2f(k01 & 0xffffu), y1 = bf2f(k01 >> 16);
  base[512] = (unsigned int)f2bf(c * y0 - s * y1) | ((unsigned int)f2bf(s * y0 + c * y1) << 16);
}

// ---------- GEMM: C[M,N] = A[M,K] * B[N,K]^T  (bf16 in, fp32 acc) ----------
// 128x128 tile, BK=64, XOR-swizzled LDS (pre-swizzled global src, m173) ->
// conflict-free ds_read_b128 at stride 128B. 2 barriers per 64-K step.
// EPI 0: bf16 store; EPI 1: fp32 acc+resid; EPI 3: fused SwiGLU (interleaved
// u/g cols -> S[row][col/2] = silu(u)*g)
template <int EPI>
__global__ __launch_bounds__(256) void gemm_bt(
    const unsigned short* __restrict__ A, const unsigned short* __restrict__ B,
    void* __restrict__ C, const float* __restrict__ resid,
    int M, int N, int K, int ldc) {
  __shared__ unsigned short As[128 * 64];
  __shared__ unsigned short Bs[128 * 64];
  const int tid = threadIdx.x;
  const int wid = tid >> 6;
  const int lane = tid & 63;
  const long rowBase = (long)blockIdx.y * 128;
  const long colBase = (long)blockIdx.x * 128;
  const int wm = (wid >> 1) * 64;
  const int wn = (wid & 1) * 64;
  const int srow = wid * 8 + (lane >> 3);   // staging row within 32-row group
  const int sc   = lane & 7;                // staging 16B chunk
  const int fr = lane & 15;                 // fragment row
  const int fg = lane >> 4;                 // fragment k-group

  const f32x4 z4 = {0.f, 0.f, 0.f, 0.f};
  f32x4 acc[4][4];
#pragma unroll
  for (int m = 0; m < 4; ++m)
#pragma unroll
    for (int n = 0; n < 4; ++n) acc[m][n] = z4;

  char* AsB = (char*)As;
  char* BsB = (char*)Bs;
  const int nkt = K >> 6;
  for (int kt = 0; kt < nkt; ++kt) {
    if (kt) __syncthreads();  // previous compute done before LDS overwrite
    const long kOff = (long)kt * 64;
#pragma unroll
    for (int i = 0; i < 4; ++i) {
      const int row = i * 32 + srow;
      const int cs = (sc ^ (row & 7)) * 8;       // pre-swizzled source chunk
      async_cp16(A + (rowBase + row) * K + kOff + cs, AsB + i * 4096 + wid * 1024);
      async_cp16(B + (colBase + row) * K + kOff + cs, BsB + i * 4096 + wid * 1024);
    }
    __syncthreads();  // compiler drains vmcnt(0) before s_barrier -> LDS ready
#pragma unroll
    for (int kk = 0; kk < 2; ++kk) {
      bf16x8 af[4], bfr[4];
#pragma unroll
      for (int m = 0; m < 4; ++m)
        af[m] = *(const bf16x8*)(AsB + (wm + m * 16 + fr) * 128 + (((kk * 4 + fg) ^ (fr & 7)) * 16));
#pragma unroll
      for (int n = 0; n < 4; ++n)
        bfr[n] = *(const bf16x8*)(BsB + (wn + n * 16 + fr) * 128 + (((kk * 4 + fg) ^ (fr & 7)) * 16));
#pragma unroll
      for (int m = 0; m < 4; ++m)
#pragma unroll
        for (int n = 0; n < 4; ++n)
          acc[m][n] = __builtin_amdgcn_mfma_f32_16x16x32_bf16(af[m], bfr[n], acc[m][n], 0, 0, 0);
    }
  }

  const int erow = fg * 4;  // C: col = lane&15, row = (lane>>4)*4 + reg
  if (EPI == 0) {
    unsigned short* Cp = (unsigned short*)C;
#pragma unroll
    for (int m = 0; m < 4; ++m) {
      const long r0 = rowBase + wm + m * 16 + erow;
#pragma unroll
      for (int n = 0; n < 4; ++n) {
        const long col = colBase + wn + n * 16 + fr;
#pragma unroll
        for (int r = 0; r < 4; ++r) Cp[(r0 + r) * ldc + col] = f2bf(acc[m][n][r]);
      }
    }
  } else if (EPI == 1) {
    float* Cf = (float*)C;
#pragma unroll
    for (int m = 0; m < 4; ++m) {
      const long r0 = rowBase + wm + m * 16 + erow;
#pragma unroll
      for (int n = 0; n < 4; ++n) {
        const long col = colBase + wn + n * 16 + fr;
#pragma unroll
        for (int r = 0; r < 4; ++r) {
          const long o = (r0 + r) * ldc + col;
          Cf[o] = acc[m][n][r] + resid[o];
        }
      }
    }
  } else {
    // fused SwiGLU: even col = u (W1 row), odd col = g (W3 row); out col/2
    unsigned short* Cp = (unsigned short*)C;
    const int even = !(fr & 1);
#pragma unroll
    for (int m = 0; m < 4; ++m) {
      const long r0 = rowBase + wm + m * 16 + erow;
#pragma unroll
      for (int n = 0; n < 4; ++n) {
        const long col = colBase + wn + n * 16 + fr;
        const long fcol = col >> 1;
#pragma unroll
        for (int r = 0; r < 4; ++r) {
          const float own = acc[m][n][r];
          const float oth = __shfl_xor(own, 1);
          if (even) {
            const float s = own * oth / (1.f + __expf(-own));
            Cp[(r0 + r) * ldc + fcol] = f2bf(s);
          }
        }
      }
    }
  }
}

// ---------- flash attention, causal, 16 heads x d_k=64 ----------
// S' = K*Q^T (swapped) with permuted K staging so P' lands in the PV B-frag
// layout. Block = 4 waves x 16 q-rows. KVBLK=64, K double-buffered in LDS
// (1 barrier/tile), V^T read directly from global (L2/L3-resident).
#define KSTR 72
__global__ __launch_bounds__(256) void attn_kernel(
    const unsigned short* __restrict__ QK, const unsigned short* __restrict__ Vt,
    unsigned short* __restrict__ O) {
  __shared__ unsigned short Ks[2][64 * KSTR];
  const int bh = blockIdx.x;
  const int b = bh >> 4, h = bh & 15;
  const int tid = threadIdx.x;
  const int wid = tid >> 6, lane = tid & 63;
  const int qblk = 31 - blockIdx.y;              // longest-first dispatch
  const int qbase = qblk * 64 + wid * 16;
  const int fr = lane & 15, g = lane >> 4;
  const long rowb = (long)b * TSEQ;
  const int hoff = h * 64;
  const float C2 = 0.18033688011112042f;         // 0.125 * log2(e)

  // K staging map (per 32-row group, permuted rows)
  const int ki = tid >> 3;                       // 0..31
  const int kcol = (tid & 7) * 8;
  const int kgrow = 8 * ((ki & 15) >> 2) + (ki & 3) + ((ki >> 4) << 2);

  const unsigned short* qrow = QK + (rowb + qbase + fr) * 2048 + hoff + g * 8;
  const bf16x8 qb0 = *reinterpret_cast<const bf16x8*>(qrow);
  const bf16x8 qb1 = *reinterpret_cast<const bf16x8*>(qrow + 32);

  const unsigned short* Kg = QK + rowb * 2048 + 1024 + hoff;
  // V^T: Vt[(h*64+d)][b*2048 + t]
  const unsigned short* Vrow = Vt + (long)(hoff + fr) * 4096 + rowb + g * 8;

  const f32x4 z4 = {0.f, 0.f, 0.f, 0.f};
  f32x4 acc[4];
#pragma unroll
  for (int d = 0; d < 4; ++d) acc[d] = z4;
  float mrun = -1e30f, lrun = 0.f;
  const int qg = qbase + fr;
  const int nkt = qblk + 1;

  uint4 kr0 = *reinterpret_cast<const uint4*>(Kg + (long)kgrow * 2048 + kcol);
  uint4 kr1 = *reinterpret_cast<const uint4*>(Kg + (long)(32 + kgrow) * 2048 + kcol);

  for (int kt = 0; kt < nkt; ++kt) {
    unsigned short* Kb = Ks[kt & 1];
    *reinterpret_cast<uint4*>(&Kb[ki * KSTR + kcol]) = kr0;
    *reinterpret_cast<uint4*>(&Kb[(32 + ki) * KSTR + kcol]) = kr1;
    __syncthreads();   // writes visible; prev tile's compute (other buf) done
    const int kbase = kt * 64;
    if (kt + 1 < nkt) {
      kr0 = *reinterpret_cast<const uint4*>(Kg + (long)(kbase + 64 + kgrow) * 2048 + kcol);
      kr1 = *reinterpret_cast<const uint4*>(Kg + (long)(kbase + 96 + kgrow) * 2048 + kcol);
    }
    // V fragments straight from global
    bf16x8 vf[4][2];
#pragma unroll
    for (int db = 0; db < 4; ++db)
#pragma unroll
      for (int ks = 0; ks < 2; ++ks)
        vf[db][ks] = *reinterpret_cast<const bf16x8*>(Vrow + (size_t)db * 16 * 4096 + kbase + ks * 32);

    // QK^T: per 32-k group: rows {fr, 16+fr}, contraction d=64 in 2 halves
    f32x4 s1[2], s2[2];
#pragma unroll
    for (int ks = 0; ks < 2; ++ks) {
      const unsigned short* ra = &Kb[(ks * 32 + fr) * KSTR];
      const unsigned short* rc = &Kb[(ks * 32 + 16 + fr) * KSTR];
      f32x4 t1 = z4, t2 = z4;
      t1 = __builtin_amdgcn_mfma_f32_16x16x32_bf16(*reinterpret_cast<const bf16x8*>(ra + g * 8), qb0, t1, 0, 0, 0);
      t1 = __builtin_amdgcn_mfma_f32_16x16x32_bf16(*reinterpret_cast<const bf16x8*>(ra + 32 + g * 8), qb1, t1, 0, 0, 0);
      t2 = __builtin_amdgcn_mfma_f32_16x16x32_bf16(*reinterpret_cast<const bf16x8*>(rc + g * 8), qb0, t2, 0, 0, 0);
      t2 = __builtin_amdgcn_mfma_f32_16x16x32_bf16(*reinterpret_cast<const bf16x8*>(rc + 32 + g * 8), qb1, t2, 0, 0, 0);
      s1[ks] = t1; s2[ks] = t2;
    }

    // lane's 16 raw scores: k = kbase + ks*32 + 8g + {j | 4+j}
    float sc[16];
    if (kt + 1 < nkt) {  // fully causal-visible tile: no mask
#pragma unroll
      for (int ks = 0; ks < 2; ++ks)
#pragma unroll
        for (int j = 0; j < 4; ++j) {
          sc[ks * 8 + j] = s1[ks][j];
          sc[ks * 8 + 4 + j] = s2[ks][j];
        }
    } else {
      const int kb8 = kbase + 8 * g;
#pragma unroll
      for (int ks = 0; ks < 2; ++ks)
#pragma unroll
        for (int j = 0; j < 4; ++j) {
          sc[ks * 8 + j]     = (kb8 + ks * 32 + j     <= qg) ? s1[ks][j] : -1e30f;
          sc[ks * 8 + 4 + j] = (kb8 + ks * 32 + 4 + j <= qg) ? s2[ks][j] : -1e30f;
        }
    }
    // max via max3 tree
    const float t0 = fmaxf(fmaxf(sc[0], sc[1]), sc[2]);
    const float t1 = fmaxf(fmaxf(sc[3], sc[4]), sc[5]);
    const float t2 = fmaxf(fmaxf(sc[6], sc[7]), sc[8]);
    const float t3 = fmaxf(fmaxf(sc[9], sc[10]), sc[11]);
    const float t4 = fmaxf(fmaxf(sc[12], sc[13]), sc[14]);
    float tmax = fmaxf(fmaxf(fmaxf(t0, t1), t2), fmaxf(fmaxf(t3, t4), sc[15]));
    tmax = fmaxf(tmax, __shfl_xor(tmax, 16));
    tmax = fmaxf(tmax, __shfl_xor(tmax, 32));
    if (__any(tmax > mrun)) {                    // T13 exact: skip when alpha==1
      const float mnew = fmaxf(mrun, tmax);
      const float alpha = exp2f((mrun - mnew) * C2);
#pragma unroll
      for (int db = 0; db < 4; ++db)
#pragma unroll
        for (int r = 0; r < 4; ++r) acc[db][r] *= alpha;
      lrun *= alpha;
      mrun = mnew;
    }
    const float m2 = mrun * C2;
    bf16x8 pbv[2];
    float psum = 0.f;
#pragma unroll
    for (int ks = 0; ks < 2; ++ks)
#pragma unroll
      for (int j = 0; j < 8; ++j) {
        const float p = exp2f(fmaf(sc[ks * 8 + j], C2, -m2));
        psum += p;
        pbv[ks][j] = (__bf16)p;                  // packs v_cvt_pk_bf16_f32
      }
    psum += __shfl_xor(psum, 16);
    psum += __shfl_xor(psum, 32);
    lrun += psum;

    // PV: acc[db] += V^T-frag * P'-frag
#pragma unroll
    for (int db = 0; db < 4; ++db) {
      acc[db] = __builtin_amdgcn_mfma_f32_16x16x32_bf16(vf[db][0], pbv[0], acc[db], 0, 0, 0);
      acc[db] = __builtin_amdgcn_mfma_f32_16x16x32_bf16(vf[db][1], pbv[1], acc[db], 0, 0, 0);
    }
  }

  const float inv = 1.f / lrun;
  unsigned short* orow = O + (rowb + qbase + fr) * DM + hoff;
#pragma unroll
  for (int db = 0; db < 4; ++db) {
    uint2 pk;
    pk.x = (unsigned int)f2bf(acc[db][0] * inv) | ((unsigned int)f2bf(acc[db][1] * inv) << 16);
    pk.y = (unsigned int)f2bf(acc[db][2] * inv) | ((unsigned int)f2bf(acc[db][3] * inv) << 16);
    *reinterpret_cast<uint2*>(orow + db * 16 + g * 4) = pk;
  }
}

// ---------- workspace layout (lifetime-reused) ----------
static constexpr size_t OFF_WQKV = 0;          // [3072,1024] bf16
static constexpr size_t OFF_WO   = 6291456;    // [1024,1024] bf16
static constexpr size_t OFF_W13  = 8388608;    // [5632,1024] bf16 interleaved (2f=W1_f, 2f+1=W3_f)
static constexpr size_t OFF_W2   = 19922944;   // [1024,2816] bf16
static constexpr size_t OFF_H    = 25690112;   // [4096,1024] bf16
static constexpr size_t OFF_X2   = 34078720;   // [4096,1024] f32
static constexpr size_t OFF_CT   = 50855936;   // [4096,32] f32
static constexpr size_t OFF_ST   = 51380224;   // [4096,32] f32
static constexpr size_t OFF_QK   = 51904512;   // [4096,2048] bf16 (later: S [4096,2816], may spill over Vt)
static constexpr size_t OFF_VT   = 68681728;   // [1024,(h,d)][4096 (b,t)] bf16, 8MB
static constexpr size_t OFF_HO   = 77070336;   // [4096,1024] bf16

extern "C" void kernel_launch(void* const* d_in, const int* in_sizes, int n_in,
                              void* d_out, int out_size, void* d_ws, size_t ws_size,
                              hipStream_t stream) {
  const float* x  = (const float*)d_in[0];
  const int* tpos = (const int*)d_in[1];
  const float* WQ = (const float*)d_in[2];
  const float* WK = (const float*)d_in[3];
  const float* WV = (const float*)d_in[4];
  const float* WO = (const float*)d_in[5];
  const float* W1 = (const float*)d_in[6];
  const float* W2 = (const float*)d_in[7];
  const float* W3 = (const float*)d_in[8];
  const float* g1 = (const float*)d_in[9];
  const float* g2 = (const float*)d_in[10];
  float* out = (float*)d_out;

  char* ws = (char*)d_ws;
  unsigned short* Wqkv = (unsigned short*)(ws + OFF_WQKV);
  unsigned short* Wo   = (unsigned short*)(ws + OFF_WO);
  unsigned short* W13i = (unsigned short*)(ws + OFF_W13);
  unsigned short* W2p  = (unsigned short*)(ws + OFF_W2);
  unsigned short* hbuf = (unsigned short*)(ws + OFF_H);
  float* x2            = (float*)(ws + OFF_X2);
  float* ct            = (float*)(ws + OFF_CT);
  float* st            = (float*)(ws + OFF_ST);
  unsigned short* QKb  = (unsigned short*)(ws + OFF_QK);
  unsigned short* Sbuf = (unsigned short*)(ws + OFF_QK);   // reuse after attn (spills into dead Vt)
  unsigned short* Vtb  = (unsigned short*)(ws + OFF_VT);
  unsigned short* Ho   = (unsigned short*)(ws + OFF_HO);

  // weights -> bf16 (packed, padded; W1/W3 row-interleaved)
  auto cvt = [&](const float* s, unsigned short* d, int Rs, int Cs, int Rd, int Cd, int RS, int RO) {
    long tot = (long)Rd * Cd;
    cvt_pad_kernel<<<(int)((tot + 255) / 256), 256, 0, stream>>>(s, d, Rs, Cs, tot, Cd, RS, RO);
  };
  cvt(WQ, Wqkv,               1024, 1024, 1024, 1024, 1, 0);
  cvt(WK, Wqkv + 1024 * 1024, 1024, 1024, 1024, 1024, 1, 0);
  cvt(WV, Wqkv + 2048 * 1024, 1024, 1024, 1024, 1024, 1, 0);
  cvt(WO, Wo,                 1024, 1024, 1024, 1024, 1, 0);
  cvt(W1, W13i,               DFF,  1024, DFFP, 1024, 2, 0);
  cvt(W3, W13i,               DFF,  1024, DFFP, 1024, 2, 1);
  cvt(W2, W2p,                1024, DFF,  1024, DFFP, 1, 0);

  // attention sublayer
  rmsnorm_kernel<<<BT_ROWS, 256, 0, stream>>>(x, g1, hbuf);
  trig_kernel<<<(BT_ROWS * 32) / 256, 256, 0, stream>>>(tpos, ct, st);
  gemm_bt<0><<<dim3(16, 32), 256, 0, stream>>>(hbuf, Wqkv, QKb, nullptr, BT_ROWS, 2048, 1024, 2048);
  // Vt = Wv * h^T : coalesced V^T
  gemm_bt<0><<<dim3(32, 8), 256, 0, stream>>>(Wqkv + 2048 * 1024, hbuf, Vtb, nullptr, 1024, BT_ROWS, 1024, BT_ROWS);
  rope_kernel<<<(BT_ROWS * 512) / 256, 256, 0, stream>>>(QKb, ct, st);
  attn_kernel<<<dim3(32, 32), 256, 0, stream>>>(QKb, Vtb, Ho);
  gemm_bt<1><<<dim3(8, 32), 256, 0, stream>>>(Ho, Wo, x2, x, BT_ROWS, 1024, 1024, 1024);

  // FFN sublayer (SwiGLU fused into W13 epilogue)
  rmsnorm_kernel<<<BT_ROWS, 256, 0, stream>>>(x2, g2, hbuf);
  gemm_bt<3><<<dim3(44, 32), 256, 0, stream>>>(hbuf, W13i, Sbuf, nullptr, BT_ROWS, 2 * DFFP, 1024, DFFP);
  gemm_bt<1><<<dim3(8, 32), 256, 0, stream>>>(Sbuf, W2p, out, x2, BT_ROWS, 1024, DFFP, 1024);
}

// Round 7
// 305.504 us; speedup vs baseline: 1.1835x; 1.0748x over previous
//
#include <hip/hip_runtime.h>
#include <cstdint>

// ---------- sizes ----------
#define BT_ROWS 4096      // B*T
#define DM      1024
#define DFF     2730
#define DFFP    2816      // padded to /128
#define TSEQ    2048

typedef float  f32x4  __attribute__((ext_vector_type(4)));
typedef __bf16 bf16x8 __attribute__((ext_vector_type(8)));

typedef __attribute__((address_space(1))) const unsigned int as1_uint;
typedef __attribute__((address_space(3))) unsigned int       as3_uint;

__device__ __forceinline__ unsigned short f2bf(float f) {
  union { float f; unsigned int u; } v; v.f = f;
  unsigned int u = v.u;
  return (unsigned short)((u + 0x7fffu + ((u >> 16) & 1u)) >> 16);  // RNE
}
__device__ __forceinline__ float bf2f(unsigned int b) {
  union { unsigned int u; float f; } v; v.u = b << 16;
  return v.f;
}

__device__ __forceinline__ void async_cp16(const void* g, void* l) {
  // 16B-wide global->LDS DMA; LDS dest is wave-uniform base + lane*16
  __builtin_amdgcn_global_load_lds((as1_uint*)(uintptr_t)g, (as3_uint*)(uintptr_t)l, 16, 0, 0);
}

// ---------- weight convert (+zero pad, +row stride/offset for interleaving) ----------
__global__ void cvt_pad_kernel(const float* __restrict__ src, unsigned short* __restrict__ dst,
                               int Rs, int Cs, long total, int Cd, int RS, int RO) {
  long idx = (long)blockIdx.x * 256 + threadIdx.x;
  if (idx >= total) return;
  int r = (int)(idx / Cd), c = (int)(idx % Cd);
  float v = (r < Rs && c < Cs) ? src[(long)r * Cs + c] : 0.f;
  dst[((long)r * RS + RO) * Cd + c] = f2bf(v);
}

// ---------- RMSNorm (fp32 in -> bf16 out), one block per row ----------
__global__ void rmsnorm_kernel(const float* __restrict__ x, const float* __restrict__ g,
                               unsigned short* __restrict__ out) {
  const int row = blockIdx.x, tid = threadIdx.x;
  const float4 xv = reinterpret_cast<const float4*>(x + (long)row * DM)[tid];
  float ss = xv.x * xv.x + xv.y * xv.y + xv.z * xv.z + xv.w * xv.w;
#pragma unroll
  for (int o = 32; o > 0; o >>= 1) ss += __shfl_xor(ss, o);
  __shared__ float wsum[4];
  if ((tid & 63) == 0) wsum[tid >> 6] = ss;
  __syncthreads();
  const float inv = rsqrtf((wsum[0] + wsum[1] + wsum[2] + wsum[3]) * (1.f / DM) + 1e-5f);
  const float4 gv = reinterpret_cast<const float4*>(g)[tid];
  ushort4 o4;
  o4.x = f2bf(xv.x * inv * gv.x);
  o4.y = f2bf(xv.y * inv * gv.y);
  o4.z = f2bf(xv.z * inv * gv.z);
  o4.w = f2bf(xv.w * inv * gv.w);
  reinterpret_cast<ushort4*>(out + (long)row * DM)[tid] = o4;
}

// ---------- RoPE cos/sin table ----------
__global__ void trig_kernel(const int* __restrict__ pos, float* __restrict__ ct, float* __restrict__ st) {
  int idx = blockIdx.x * 256 + threadIdx.x;
  if (idx >= BT_ROWS * 32) return;
  int r = idx >> 5, i = idx & 31;
  float f = powf(10000.f, -(float)(2 * i) * (1.f / 64.f));
  float ang = (float)pos[r] * f;
  float sv, cv;
  sincosf(ang, &sv, &cv);
  ct[idx] = cv; st[idx] = sv;
}

// ---------- RoPE applied in-place to Q,K halves of QK buf (bf16, ld 2048) ----------
__global__ void rope_kernel(unsigned short* __restrict__ QK,
                            const float* __restrict__ ct, const float* __restrict__ st) {
  int idx = blockIdx.x * 256 + threadIdx.x;  // over 4096*512 (row, head*pair)
  if (idx >= BT_ROWS * 512) return;
  int r = idx >> 9, p = idx & 511;
  int h = p >> 5, i = p & 31;
  float c = ct[r * 32 + i], s = st[r * 32 + i];
  unsigned int* base = reinterpret_cast<unsigned int*>(QK + (long)r * 2048 + h * 64 + 2 * i);
  unsigned int q01 = base[0];
  float x0 = bf2f(q01 & 0xffffu), x1 = bf2f(q01 >> 16);
  base[0] = (unsigned int)f2bf(c * x0 - s * x1) | ((unsigned int)f2bf(s * x0 + c * x1) << 16);
  unsigned int k01 = base[512];  // +1024 shorts = K block
  float y0 = bf2f(k01 & 0xffffu), y1 = bf2f(k01 >> 16);
  base[512] = (unsigned int)f2bf(c * y0 - s * y1) | ((unsigned int)f2bf(s * y0 + c * y1) << 16);
}

// ---------- GEMM: C[M,N] = A[M,K] * B[N,K]^T  (bf16 in, fp32 acc) ----------
// 128xBN tile (BN=128 or 64), BK=64, XOR-swizzled LDS (pre-swizzled global
// src) -> conflict-free ds_read_b128 at stride 128B. 2 barriers per K-step.
// BN=64 doubles the grid for narrow-N GEMMs (2 blocks/CU -> overlap, m114).
// EPI 0: bf16 store; EPI 1: fp32 acc+resid; EPI 3: fused SwiGLU (interleaved
// u/g cols -> S[row][col/2] = silu(u)*g)
template <int EPI, int BN>
__global__ __launch_bounds__(256) void gemm_bt(
    const unsigned short* __restrict__ A, const unsigned short* __restrict__ B,
    void* __restrict__ C, const float* __restrict__ resid,
    int M, int N, int K, int ldc) {
  constexpr int WNF = BN / 32;              // B-frags per wave (4 or 2)
  __shared__ unsigned short As[128 * 64];
  __shared__ unsigned short Bs[BN * 64];
  const int tid = threadIdx.x;
  const int wid = tid >> 6;
  const int lane = tid & 63;
  const long rowBase = (long)blockIdx.y * 128;
  const long colBase = (long)blockIdx.x * BN;
  const int wm = (wid >> 1) * 64;
  const int wn = (wid & 1) * (BN / 2);
  const int srow = wid * 8 + (lane >> 3);   // staging row within 32-row group
  const int sc   = lane & 7;                // staging 16B chunk
  const int fr = lane & 15;                 // fragment row
  const int fg = lane >> 4;                 // fragment k-group

  const f32x4 z4 = {0.f, 0.f, 0.f, 0.f};
  f32x4 acc[4][WNF];
#pragma unroll
  for (int m = 0; m < 4; ++m)
#pragma unroll
    for (int n = 0; n < WNF; ++n) acc[m][n] = z4;

  char* AsB = (char*)As;
  char* BsB = (char*)Bs;
  const int nkt = K >> 6;
  for (int kt = 0; kt < nkt; ++kt) {
    if (kt) __syncthreads();  // previous compute done before LDS overwrite
    const long kOff = (long)kt * 64;
#pragma unroll
    for (int i = 0; i < 4; ++i) {
      const int row = i * 32 + srow;
      const int cs = (sc ^ (row & 7)) * 8;       // pre-swizzled source chunk
      async_cp16(A + (rowBase + row) * K + kOff + cs, AsB + i * 4096 + wid * 1024);
    }
#pragma unroll
    for (int i = 0; i < WNF; ++i) {              // BN/32 staging groups (FIX)
      const int row = i * 32 + srow;
      const int cs = (sc ^ (row & 7)) * 8;
      async_cp16(B + (colBase + row) * K + kOff + cs, BsB + i * 4096 + wid * 1024);
    }
    __syncthreads();  // compiler drains vmcnt(0) before s_barrier -> LDS ready
#pragma unroll
    for (int kk = 0; kk < 2; ++kk) {
      bf16x8 af[4], bfr[WNF];
#pragma unroll
      for (int m = 0; m < 4; ++m)
        af[m] = *(const bf16x8*)(AsB + (wm + m * 16 + fr) * 128 + (((kk * 4 + fg) ^ (fr & 7)) * 16));
#pragma unroll
      for (int n = 0; n < WNF; ++n)
        bfr[n] = *(const bf16x8*)(BsB + (wn + n * 16 + fr) * 128 + (((kk * 4 + fg) ^ (fr & 7)) * 16));
#pragma unroll
      for (int m = 0; m < 4; ++m)
#pragma unroll
        for (int n = 0; n < WNF; ++n)
          acc[m][n] = __builtin_amdgcn_mfma_f32_16x16x32_bf16(af[m], bfr[n], acc[m][n], 0, 0, 0);
    }
  }

  const int erow = fg * 4;  // C: col = lane&15, row = (lane>>4)*4 + reg
  if (EPI == 0) {
    unsigned short* Cp = (unsigned short*)C;
#pragma unroll
    for (int m = 0; m < 4; ++m) {
      const long r0 = rowBase + wm + m * 16 + erow;
#pragma unroll
      for (int n = 0; n < WNF; ++n) {
        const long col = colBase + wn + n * 16 + fr;
#pragma unroll
        for (int r = 0; r < 4; ++r) Cp[(r0 + r) * ldc + col] = f2bf(acc[m][n][r]);
      }
    }
  } else if (EPI == 1) {
    float* Cf = (float*)C;
#pragma unroll
    for (int m = 0; m < 4; ++m) {
      const long r0 = rowBase + wm + m * 16 + erow;
#pragma unroll
      for (int n = 0; n < WNF; ++n) {
        const long col = colBase + wn + n * 16 + fr;
#pragma unroll
        for (int r = 0; r < 4; ++r) {
          const long o = (r0 + r) * ldc + col;
          Cf[o] = acc[m][n][r] + resid[o];
        }
      }
    }
  } else {
    // fused SwiGLU: even col = u (W1 row), odd col = g (W3 row); out col/2
    unsigned short* Cp = (unsigned short*)C;
    const int even = !(fr & 1);
#pragma unroll
    for (int m = 0; m < 4; ++m) {
      const long r0 = rowBase + wm + m * 16 + erow;
#pragma unroll
      for (int n = 0; n < WNF; ++n) {
        const long col = colBase + wn + n * 16 + fr;
        const long fcol = col >> 1;
#pragma unroll
        for (int r = 0; r < 4; ++r) {
          const float own = acc[m][n][r];
          const float oth = __shfl_xor(own, 1);
          if (even) {
            const float s = own * oth / (1.f + __expf(-own));
            Cp[(r0 + r) * ldc + fcol] = f2bf(s);
          }
        }
      }
    }
  }
}

// ---------- flash attention, causal, 16 heads x d_k=64 ----------
// S' = K*Q^T (swapped) with permuted K staging so P' lands in the PV B-frag
// layout. Block = 4 waves x 16 q-rows. KVBLK=64, K double-buffered in LDS
// (1 barrier/tile), V^T read directly from global (L2/L3-resident).
#define KSTR 72
__global__ __launch_bounds__(256) void attn_kernel(
    const unsigned short* __restrict__ QK, const unsigned short* __restrict__ Vt,
    unsigned short* __restrict__ O) {
  __shared__ unsigned short Ks[2][64 * KSTR];
  const int bh = blockIdx.x;
  const int b = bh >> 4, h = bh & 15;
  const int tid = threadIdx.x;
  const int wid = tid >> 6, lane = tid & 63;
  const int qblk = 31 - blockIdx.y;              // longest-first dispatch
  const int qbase = qblk * 64 + wid * 16;
  const int fr = lane & 15, g = lane >> 4;
  const long rowb = (long)b * TSEQ;
  const int hoff = h * 64;
  const float C2 = 0.18033688011112042f;         // 0.125 * log2(e)

  // K staging map (per 32-row group, permuted rows)
  const int ki = tid >> 3;                       // 0..31
  const int kcol = (tid & 7) * 8;
  const int kgrow = 8 * ((ki & 15) >> 2) + (ki & 3) + ((ki >> 4) << 2);

  const unsigned short* qrow = QK + (rowb + qbase + fr) * 2048 + hoff + g * 8;
  const bf16x8 qb0 = *reinterpret_cast<const bf16x8*>(qrow);
  const bf16x8 qb1 = *reinterpret_cast<const bf16x8*>(qrow + 32);

  const unsigned short* Kg = QK + rowb * 2048 + 1024 + hoff;
  // V^T: Vt[(h*64+d)][b*2048 + t]
  const unsigned short* Vrow = Vt + (long)(hoff + fr) * 4096 + rowb + g * 8;

  const f32x4 z4 = {0.f, 0.f, 0.f, 0.f};
  f32x4 acc[4];
#pragma unroll
  for (int d = 0; d < 4; ++d) acc[d] = z4;
  float mrun = -1e30f, lrun = 0.f;
  const int qg = qbase + fr;
  const int nkt = qblk + 1;

  uint4 kr0 = *reinterpret_cast<const uint4*>(Kg + (long)kgrow * 2048 + kcol);
  uint4 kr1 = *reinterpret_cast<const uint4*>(Kg + (long)(32 + kgrow) * 2048 + kcol);

  for (int kt = 0; kt < nkt; ++kt) {
    unsigned short* Kb = Ks[kt & 1];
    *reinterpret_cast<uint4*>(&Kb[ki * KSTR + kcol]) = kr0;
    *reinterpret_cast<uint4*>(&Kb[(32 + ki) * KSTR + kcol]) = kr1;
    __syncthreads();   // writes visible; prev tile's compute (other buf) done
    const int kbase = kt * 64;
    if (kt + 1 < nkt) {
      kr0 = *reinterpret_cast<const uint4*>(Kg + (long)(kbase + 64 + kgrow) * 2048 + kcol);
      kr1 = *reinterpret_cast<const uint4*>(Kg + (long)(kbase + 96 + kgrow) * 2048 + kcol);
    }
    // V fragments straight from global
    bf16x8 vf[4][2];
#pragma unroll
    for (int db = 0; db < 4; ++db)
#pragma unroll
      for (int ks = 0; ks < 2; ++ks)
        vf[db][ks] = *reinterpret_cast<const bf16x8*>(Vrow + (size_t)db * 16 * 4096 + kbase + ks * 32);

    // QK^T: per 32-k group: rows {fr, 16+fr}, contraction d=64 in 2 halves
    f32x4 s1[2], s2[2];
#pragma unroll
    for (int ks = 0; ks < 2; ++ks) {
      const unsigned short* ra = &Kb[(ks * 32 + fr) * KSTR];
      const unsigned short* rc = &Kb[(ks * 32 + 16 + fr) * KSTR];
      f32x4 t1 = z4, t2 = z4;
      t1 = __builtin_amdgcn_mfma_f32_16x16x32_bf16(*reinterpret_cast<const bf16x8*>(ra + g * 8), qb0, t1, 0, 0, 0);
      t1 = __builtin_amdgcn_mfma_f32_16x16x32_bf16(*reinterpret_cast<const bf16x8*>(ra + 32 + g * 8), qb1, t1, 0, 0, 0);
      t2 = __builtin_amdgcn_mfma_f32_16x16x32_bf16(*reinterpret_cast<const bf16x8*>(rc + g * 8), qb0, t2, 0, 0, 0);
      t2 = __builtin_amdgcn_mfma_f32_16x16x32_bf16(*reinterpret_cast<const bf16x8*>(rc + 32 + g * 8), qb1, t2, 0, 0, 0);
      s1[ks] = t1; s2[ks] = t2;
    }

    // lane's 16 raw scores: k = kbase + ks*32 + 8g + {j | 4+j}
    float sc[16];
    if (kt + 1 < nkt) {  // fully causal-visible tile: no mask
#pragma unroll
      for (int ks = 0; ks < 2; ++ks)
#pragma unroll
        for (int j = 0; j < 4; ++j) {
          sc[ks * 8 + j] = s1[ks][j];
          sc[ks * 8 + 4 + j] = s2[ks][j];
        }
    } else {
      const int kb8 = kbase + 8 * g;
#pragma unroll
      for (int ks = 0; ks < 2; ++ks)
#pragma unroll
        for (int j = 0; j < 4; ++j) {
          sc[ks * 8 + j]     = (kb8 + ks * 32 + j     <= qg) ? s1[ks][j] : -1e30f;
          sc[ks * 8 + 4 + j] = (kb8 + ks * 32 + 4 + j <= qg) ? s2[ks][j] : -1e30f;
        }
    }
    // max via max3 tree
    const float t0 = fmaxf(fmaxf(sc[0], sc[1]), sc[2]);
    const float t1 = fmaxf(fmaxf(sc[3], sc[4]), sc[5]);
    const float t2 = fmaxf(fmaxf(sc[6], sc[7]), sc[8]);
    const float t3 = fmaxf(fmaxf(sc[9], sc[10]), sc[11]);
    const float t4 = fmaxf(fmaxf(sc[12], sc[13]), sc[14]);
    float tmax = fmaxf(fmaxf(fmaxf(t0, t1), t2), fmaxf(fmaxf(t3, t4), sc[15]));
    tmax = fmaxf(tmax, __shfl_xor(tmax, 16));
    tmax = fmaxf(tmax, __shfl_xor(tmax, 32));
    if (__any(tmax > mrun)) {                    // T13 exact: skip when alpha==1
      const float mnew = fmaxf(mrun, tmax);
      const float alpha = exp2f((mrun - mnew) * C2);
#pragma unroll
      for (int db = 0; db < 4; ++db)
#pragma unroll
        for (int r = 0; r < 4; ++r) acc[db][r] *= alpha;
      lrun *= alpha;
      mrun = mnew;
    }
    const float m2 = mrun * C2;
    bf16x8 pbv[2];
    float psum = 0.f;
#pragma unroll
    for (int ks = 0; ks < 2; ++ks)
#pragma unroll
      for (int j = 0; j < 8; ++j) {
        const float p = exp2f(fmaf(sc[ks * 8 + j], C2, -m2));
        psum += p;
        pbv[ks][j] = (__bf16)p;                  // packs v_cvt_pk_bf16_f32
      }
    psum += __shfl_xor(psum, 16);
    psum += __shfl_xor(psum, 32);
    lrun += psum;

    // PV: acc[db] += V^T-frag * P'-frag
#pragma unroll
    for (int db = 0; db < 4; ++db) {
      acc[db] = __builtin_amdgcn_mfma_f32_16x16x32_bf16(vf[db][0], pbv[0], acc[db], 0, 0, 0);
      acc[db] = __builtin_amdgcn_mfma_f32_16x16x32_bf16(vf[db][1], pbv[1], acc[db], 0, 0, 0);
    }
  }

  const float inv = 1.f / lrun;
  unsigned short* orow = O + (rowb + qbase + fr) * DM + hoff;
#pragma unroll
  for (int db = 0; db < 4; ++db) {
    uint2 pk;
    pk.x = (unsigned int)f2bf(acc[db][0] * inv) | ((unsigned int)f2bf(acc[db][1] * inv) << 16);
    pk.y = (unsigned int)f2bf(acc[db][2] * inv) | ((unsigned int)f2bf(acc[db][3] * inv) << 16);
    *reinterpret_cast<uint2*>(orow + db * 16 + g * 4) = pk;
  }
}

// ---------- workspace layout (lifetime-reused) ----------
static constexpr size_t OFF_WQKV = 0;          // [3072,1024] bf16
static constexpr size_t OFF_WO   = 6291456;    // [1024,1024] bf16
static constexpr size_t OFF_W13  = 8388608;    // [5632,1024] bf16 interleaved (2f=W1_f, 2f+1=W3_f)
static constexpr size_t OFF_W2   = 19922944;   // [1024,2816] bf16
static constexpr size_t OFF_H    = 25690112;   // [4096,1024] bf16
static constexpr size_t OFF_X2   = 34078720;   // [4096,1024] f32
static constexpr size_t OFF_CT   = 50855936;   // [4096,32] f32
static constexpr size_t OFF_ST   = 51380224;   // [4096,32] f32
static constexpr size_t OFF_QK   = 51904512;   // [4096,2048] bf16 (later: S [4096,2816], spills into dead Vt)
static constexpr size_t OFF_VT   = 68681728;   // [1024,(h,d)][4096 (b,t)] bf16, 8MB
static constexpr size_t OFF_HO   = 77070336;   // [4096,1024] bf16

extern "C" void kernel_launch(void* const* d_in, const int* in_sizes, int n_in,
                              void* d_out, int out_size, void* d_ws, size_t ws_size,
                              hipStream_t stream) {
  const float* x  = (const float*)d_in[0];
  const int* tpos = (const int*)d_in[1];
  const float* WQ = (const float*)d_in[2];
  const float* WK = (const float*)d_in[3];
  const float* WV = (const float*)d_in[4];
  const float* WO = (const float*)d_in[5];
  const float* W1 = (const float*)d_in[6];
  const float* W2 = (const float*)d_in[7];
  const float* W3 = (const float*)d_in[8];
  const float* g1 = (const float*)d_in[9];
  const float* g2 = (const float*)d_in[10];
  float* out = (float*)d_out;

  char* ws = (char*)d_ws;
  unsigned short* Wqkv = (unsigned short*)(ws + OFF_WQKV);
  unsigned short* Wo   = (unsigned short*)(ws + OFF_WO);
  unsigned short* W13i = (unsigned short*)(ws + OFF_W13);
  unsigned short* W2p  = (unsigned short*)(ws + OFF_W2);
  unsigned short* hbuf = (unsigned short*)(ws + OFF_H);
  float* x2            = (float*)(ws + OFF_X2);
  float* ct            = (float*)(ws + OFF_CT);
  float* st            = (float*)(ws + OFF_ST);
  unsigned short* QKb  = (unsigned short*)(ws + OFF_QK);
  unsigned short* Sbuf = (unsigned short*)(ws + OFF_QK);   // reuse after attn
  unsigned short* Vtb  = (unsigned short*)(ws + OFF_VT);
  unsigned short* Ho   = (unsigned short*)(ws + OFF_HO);

  // weights -> bf16 (packed, padded; W1/W3 row-interleaved)
  auto cvt = [&](const float* s, unsigned short* d, int Rs, int Cs, int Rd, int Cd, int RS, int RO) {
    long tot = (long)Rd * Cd;
    cvt_pad_kernel<<<(int)((tot + 255) / 256), 256, 0, stream>>>(s, d, Rs, Cs, tot, Cd, RS, RO);
  };
  cvt(WQ, Wqkv,               1024, 1024, 1024, 1024, 1, 0);
  cvt(WK, Wqkv + 1024 * 1024, 1024, 1024, 1024, 1024, 1, 0);
  cvt(WV, Wqkv + 2048 * 1024, 1024, 1024, 1024, 1024, 1, 0);
  cvt(WO, Wo,                 1024, 1024, 1024, 1024, 1, 0);
  cvt(W1, W13i,               DFF,  1024, DFFP, 1024, 2, 0);
  cvt(W3, W13i,               DFF,  1024, DFFP, 1024, 2, 1);
  cvt(W2, W2p,                1024, DFF,  1024, DFFP, 1, 0);

  // attention sublayer
  rmsnorm_kernel<<<BT_ROWS, 256, 0, stream>>>(x, g1, hbuf);
  trig_kernel<<<(BT_ROWS * 32) / 256, 256, 0, stream>>>(tpos, ct, st);
  gemm_bt<0, 128><<<dim3(16, 32), 256, 0, stream>>>(hbuf, Wqkv, QKb, nullptr, BT_ROWS, 2048, 1024, 2048);
  // Vt = Wv * h^T : coalesced V^T, BN=64 -> 512 blocks (2/CU)
  gemm_bt<0, 64><<<dim3(64, 8), 256, 0, stream>>>(Wqkv + 2048 * 1024, hbuf, Vtb, nullptr, 1024, BT_ROWS, 1024, BT_ROWS);
  rope_kernel<<<(BT_ROWS * 512) / 256, 256, 0, stream>>>(QKb, ct, st);
  attn_kernel<<<dim3(32, 32), 256, 0, stream>>>(QKb, Vtb, Ho);
  gemm_bt<1, 64><<<dim3(16, 32), 256, 0, stream>>>(Ho, Wo, x2, x, BT_ROWS, 1024, 1024, 1024);

  // FFN sublayer (SwiGLU fused into W13 epilogue)
  rmsnorm_kernel<<<BT_ROWS, 256, 0, stream>>>(x2, g2, hbuf);
  gemm_bt<3, 128><<<dim3(44, 32), 256, 0, stream>>>(hbuf, W13i, Sbuf, nullptr, BT_ROWS, 2 * DFFP, 1024, DFFP);
  gemm_bt<1, 64><<<dim3(16, 32), 256, 0, stream>>>(Sbuf, W2p, out, x2, BT_ROWS, 1024, DFFP, 1024);
}

// Round 8
// 294.052 us; speedup vs baseline: 1.2296x; 1.0389x over previous
//
#include <hip/hip_runtime.h>
#include <cstdint>

// ---------- sizes ----------
#define BT_ROWS 4096      // B*T
#define DM      1024
#define DFF     2730
#define DFFP    2816      // padded to /128
#define TSEQ    2048

typedef float  f32x4  __attribute__((ext_vector_type(4)));
typedef __bf16 bf16x8 __attribute__((ext_vector_type(8)));

typedef __attribute__((address_space(1))) const unsigned int as1_uint;
typedef __attribute__((address_space(3))) unsigned int       as3_uint;

__device__ __forceinline__ unsigned short f2bf(float f) {
  union { float f; unsigned int u; } v; v.f = f;
  unsigned int u = v.u;
  return (unsigned short)((u + 0x7fffu + ((u >> 16) & 1u)) >> 16);  // RNE
}
__device__ __forceinline__ float bf2f(unsigned int b) {
  union { unsigned int u; float f; } v; v.u = b << 16;
  return v.f;
}

__device__ __forceinline__ void async_cp16(const void* g, void* l) {
  // 16B-wide global->LDS DMA; LDS dest is wave-uniform base + lane*16
  __builtin_amdgcn_global_load_lds((as1_uint*)(uintptr_t)g, (as3_uint*)(uintptr_t)l, 16, 0, 0);
}

// ---------- fused prep: all weight converts (+pad/interleave) + RoPE trig ----------
// Segment sizes are multiples of 256 -> no intra-block divergence.
__global__ void prep_kernel(const float* __restrict__ WQ, const float* __restrict__ WK,
                            const float* __restrict__ WV, const float* __restrict__ WOp,
                            const float* __restrict__ W1, const float* __restrict__ W3,
                            const float* __restrict__ W2, const int* __restrict__ pos,
                            unsigned short* __restrict__ Wqkv, unsigned short* __restrict__ Wo,
                            unsigned short* __restrict__ W13i, unsigned short* __restrict__ W2p,
                            float* __restrict__ ct, float* __restrict__ st) {
  long idx = (long)blockIdx.x * 256 + threadIdx.x;
  if (idx < 4194304) {                       // 4 square 1024x1024 mats
    const int j = (int)(idx >> 20);
    const long t = idx & 1048575;
    const float* s = (j == 0) ? WQ : (j == 1) ? WK : (j == 2) ? WV : WOp;
    unsigned short* d = (j < 3) ? (Wqkv + (size_t)j * 1048576) : Wo;
    d[t] = f2bf(s[t]);
    return;
  }
  idx -= 4194304;
  if (idx < 2L * DFFP * 1024) {              // W1/W3 row-interleaved + pad
    const int half = (int)(idx / (DFFP * 1024));
    const long t = idx % (DFFP * 1024);
    const int r = (int)(t >> 10), c = (int)(t & 1023);
    const float v = (r < DFF) ? (half ? W3 : W1)[(long)r * 1024 + c] : 0.f;
    W13i[((long)2 * r + half) * 1024 + c] = f2bf(v);
    return;
  }
  idx -= 2L * DFFP * 1024;
  if (idx < 1024L * DFFP) {                  // W2 col-padded
    const int c = (int)(idx % DFFP), r = (int)(idx / DFFP);
    const float v = (c < DFF) ? W2[(long)r * DFF + c] : 0.f;
    W2p[idx] = f2bf(v);
    return;
  }
  idx -= 1024L * DFFP;
  if (idx < BT_ROWS * 32) {                  // RoPE cos/sin table
    const int r = (int)(idx >> 5), i = (int)(idx & 31);
    const float f = powf(10000.f, -(float)(2 * i) * (1.f / 64.f));
    float sv, cv;
    sincosf((float)pos[r] * f, &sv, &cv);
    ct[idx] = cv; st[idx] = sv;
  }
}
#define PREP_TOTAL (4194304L + 2L * DFFP * 1024 + 1024L * DFFP + BT_ROWS * 32)

// ---------- RMSNorm (fp32 in -> bf16 out), one block per row ----------
__global__ void rmsnorm_kernel(const float* __restrict__ x, const float* __restrict__ g,
                               unsigned short* __restrict__ out) {
  const int row = blockIdx.x, tid = threadIdx.x;
  const float4 xv = reinterpret_cast<const float4*>(x + (long)row * DM)[tid];
  float ss = xv.x * xv.x + xv.y * xv.y + xv.z * xv.z + xv.w * xv.w;
#pragma unroll
  for (int o = 32; o > 0; o >>= 1) ss += __shfl_xor(ss, o);
  __shared__ float wsum[4];
  if ((tid & 63) == 0) wsum[tid >> 6] = ss;
  __syncthreads();
  const float inv = rsqrtf((wsum[0] + wsum[1] + wsum[2] + wsum[3]) * (1.f / DM) + 1e-5f);
  const float4 gv = reinterpret_cast<const float4*>(g)[tid];
  ushort4 o4;
  o4.x = f2bf(xv.x * inv * gv.x);
  o4.y = f2bf(xv.y * inv * gv.y);
  o4.z = f2bf(xv.z * inv * gv.z);
  o4.w = f2bf(xv.w * inv * gv.w);
  reinterpret_cast<ushort4*>(out + (long)row * DM)[tid] = o4;
}

// ---------- RoPE applied in-place to Q,K halves of QK buf (bf16, ld 2048) ----------
__global__ void rope_kernel(unsigned short* __restrict__ QK,
                            const float* __restrict__ ct, const float* __restrict__ st) {
  int idx = blockIdx.x * 256 + threadIdx.x;  // over 4096*512 (row, head*pair)
  if (idx >= BT_ROWS * 512) return;
  int r = idx >> 9, p = idx & 511;
  int h = p >> 5, i = p & 31;
  float c = ct[r * 32 + i], s = st[r * 32 + i];
  unsigned int* base = reinterpret_cast<unsigned int*>(QK + (long)r * 2048 + h * 64 + 2 * i);
  unsigned int q01 = base[0];
  float x0 = bf2f(q01 & 0xffffu), x1 = bf2f(q01 >> 16);
  base[0] = (unsigned int)f2bf(c * x0 - s * x1) | ((unsigned int)f2bf(s * x0 + c * x1) << 16);
  unsigned int k01 = base[512];  // +1024 shorts = K block
  float y0 = bf2f(k01 & 0xffffu), y1 = bf2f(k01 >> 16);
  base[512] = (unsigned int)f2bf(c * y0 - s * y1) | ((unsigned int)f2bf(s * y0 + c * y1) << 16);
}

// ---------- GEMM: C[M,N] = A[M,K] * B[N,K]^T  (bf16 in, fp32 acc) ----------
// 128xBN tile (BN=128 or 64), BK=64, XOR-swizzled LDS (pre-swizzled global
// src) -> conflict-free ds_read_b128 at stride 128B. 2 barriers per K-step.
// EPI 0: bf16 store; EPI 1: fp32 acc+resid; EPI 3: fused SwiGLU
template <int EPI, int BN>
__global__ __launch_bounds__(256) void gemm_bt(
    const unsigned short* __restrict__ A, const unsigned short* __restrict__ B,
    void* __restrict__ C, const float* __restrict__ resid,
    int M, int N, int K, int ldc) {
  constexpr int WNF = BN / 32;              // B-frags per wave (4 or 2)
  __shared__ unsigned short As[128 * 64];
  __shared__ unsigned short Bs[BN * 64];
  const int tid = threadIdx.x;
  const int wid = tid >> 6;
  const int lane = tid & 63;
  const long rowBase = (long)blockIdx.y * 128;
  const long colBase = (long)blockIdx.x * BN;
  const int wm = (wid >> 1) * 64;
  const int wn = (wid & 1) * (BN / 2);
  const int srow = wid * 8 + (lane >> 3);   // staging row within 32-row group
  const int sc   = lane & 7;                // staging 16B chunk
  const int fr = lane & 15;                 // fragment row
  const int fg = lane >> 4;                 // fragment k-group

  const f32x4 z4 = {0.f, 0.f, 0.f, 0.f};
  f32x4 acc[4][WNF];
#pragma unroll
  for (int m = 0; m < 4; ++m)
#pragma unroll
    for (int n = 0; n < WNF; ++n) acc[m][n] = z4;

  char* AsB = (char*)As;
  char* BsB = (char*)Bs;
  const int nkt = K >> 6;
  for (int kt = 0; kt < nkt; ++kt) {
    if (kt) __syncthreads();  // previous compute done before LDS overwrite
    const long kOff = (long)kt * 64;
#pragma unroll
    for (int i = 0; i < 4; ++i) {
      const int row = i * 32 + srow;
      const int cs = (sc ^ (row & 7)) * 8;       // pre-swizzled source chunk
      async_cp16(A + (rowBase + row) * K + kOff + cs, AsB + i * 4096 + wid * 1024);
    }
#pragma unroll
    for (int i = 0; i < WNF; ++i) {              // BN/32 staging groups
      const int row = i * 32 + srow;
      const int cs = (sc ^ (row & 7)) * 8;
      async_cp16(B + (colBase + row) * K + kOff + cs, BsB + i * 4096 + wid * 1024);
    }
    __syncthreads();  // compiler drains vmcnt(0) before s_barrier -> LDS ready
#pragma unroll
    for (int kk = 0; kk < 2; ++kk) {
      bf16x8 af[4], bfr[WNF];
#pragma unroll
      for (int m = 0; m < 4; ++m)
        af[m] = *(const bf16x8*)(AsB + (wm + m * 16 + fr) * 128 + (((kk * 4 + fg) ^ (fr & 7)) * 16));
#pragma unroll
      for (int n = 0; n < WNF; ++n)
        bfr[n] = *(const bf16x8*)(BsB + (wn + n * 16 + fr) * 128 + (((kk * 4 + fg) ^ (fr & 7)) * 16));
#pragma unroll
      for (int m = 0; m < 4; ++m)
#pragma unroll
        for (int n = 0; n < WNF; ++n)
          acc[m][n] = __builtin_amdgcn_mfma_f32_16x16x32_bf16(af[m], bfr[n], acc[m][n], 0, 0, 0);
    }
  }

  const int erow = fg * 4;  // C: col = lane&15, row = (lane>>4)*4 + reg
  if (EPI == 0) {
    unsigned short* Cp = (unsigned short*)C;
#pragma unroll
    for (int m = 0; m < 4; ++m) {
      const long r0 = rowBase + wm + m * 16 + erow;
#pragma unroll
      for (int n = 0; n < WNF; ++n) {
        const long col = colBase + wn + n * 16 + fr;
#pragma unroll
        for (int r = 0; r < 4; ++r) Cp[(r0 + r) * ldc + col] = f2bf(acc[m][n][r]);
      }
    }
  } else if (EPI == 1) {
    float* Cf = (float*)C;
#pragma unroll
    for (int m = 0; m < 4; ++m) {
      const long r0 = rowBase + wm + m * 16 + erow;
#pragma unroll
      for (int n = 0; n < WNF; ++n) {
        const long col = colBase + wn + n * 16 + fr;
#pragma unroll
        for (int r = 0; r < 4; ++r) {
          const long o = (r0 + r) * ldc + col;
          Cf[o] = acc[m][n][r] + resid[o];
        }
      }
    }
  } else {
    // fused SwiGLU: even col = u (W1 row), odd col = g (W3 row); out col/2
    unsigned short* Cp = (unsigned short*)C;
    const int even = !(fr & 1);
#pragma unroll
    for (int m = 0; m < 4; ++m) {
      const long r0 = rowBase + wm + m * 16 + erow;
#pragma unroll
      for (int n = 0; n < WNF; ++n) {
        const long col = colBase + wn + n * 16 + fr;
        const long fcol = col >> 1;
#pragma unroll
        for (int r = 0; r < 4; ++r) {
          const float own = acc[m][n][r];
          const float oth = __shfl_xor(own, 1);
          if (even) {
            const float s = own * oth / (1.f + __expf(-own));
            Cp[(r0 + r) * ldc + fcol] = f2bf(s);
          }
        }
      }
    }
  }
}

// ---------- flash attention, causal, K-split x2 (flash-decoding) ----------
// S' = K*Q^T (swapped) with permuted K staging so P' lands in the PV B-frag
// layout. Block = 4 waves x 16 q-rows; each (bh, qblk) splits its K-range
// into 2 halves -> 2048 blocks, <=16 tiles each. Partials: unnormalized acc
// (bf16) + per-row (m,l) f32; combined by attn_combine.
#define KSTR 72
__global__ __launch_bounds__(256) void attn_kernel(
    const unsigned short* __restrict__ QK, const unsigned short* __restrict__ Vt,
    unsigned short* __restrict__ Apart, float2* __restrict__ ML) {
  __shared__ unsigned short Ks[2][64 * KSTR];
  const int bh = blockIdx.x;
  const int b = bh >> 4, h = bh & 15;
  const int tid = threadIdx.x;
  const int wid = tid >> 6, lane = tid & 63;
  const int y = blockIdx.y;
  const int qblk = 31 - (y >> 1);                // longest-first dispatch
  const int sp = y & 1;                          // K-split half
  const int qbase = qblk * 64 + wid * 16;
  const int fr = lane & 15, g = lane >> 4;
  const long rowb = (long)b * TSEQ;
  const int hoff = h * 64;
  const float C2 = 0.18033688011112042f;         // 0.125 * log2(e)

  const int nkt = qblk + 1;
  const int half = (nkt + 1) >> 1;
  const int kt0 = sp * half;
  const int kt1 = (kt0 + half < nkt) ? (kt0 + half) : nkt;

  // K staging map (per 32-row group, permuted rows)
  const int ki = tid >> 3;                       // 0..31
  const int kcol = (tid & 7) * 8;
  const int kgrow = 8 * ((ki & 15) >> 2) + (ki & 3) + ((ki >> 4) << 2);

  const unsigned short* qrow = QK + (rowb + qbase + fr) * 2048 + hoff + g * 8;
  const bf16x8 qb0 = *reinterpret_cast<const bf16x8*>(qrow);
  const bf16x8 qb1 = *reinterpret_cast<const bf16x8*>(qrow + 32);

  const unsigned short* Kg = QK + rowb * 2048 + 1024 + hoff;
  // V^T: Vt[(h*64+d)][b*2048 + t]
  const unsigned short* Vrow = Vt + (long)(hoff + fr) * 4096 + rowb + g * 8;

  const f32x4 z4 = {0.f, 0.f, 0.f, 0.f};
  f32x4 acc[4];
#pragma unroll
  for (int d = 0; d < 4; ++d) acc[d] = z4;
  float mrun = -1e30f, lrun = 0.f;
  const int qg = qbase + fr;

  uint4 kr0 = *reinterpret_cast<const uint4*>(Kg + (long)(kt0 * 64 + kgrow) * 2048 + kcol);
  uint4 kr1 = *reinterpret_cast<const uint4*>(Kg + (long)(kt0 * 64 + 32 + kgrow) * 2048 + kcol);

  for (int kt = kt0; kt < kt1; ++kt) {
    unsigned short* Kb = Ks[kt & 1];
    *reinterpret_cast<uint4*>(&Kb[ki * KSTR + kcol]) = kr0;
    *reinterpret_cast<uint4*>(&Kb[(32 + ki) * KSTR + kcol]) = kr1;
    __syncthreads();   // writes visible; prev tile's compute (other buf) done
    const int kbase = kt * 64;
    if (kt + 1 < kt1) {
      kr0 = *reinterpret_cast<const uint4*>(Kg + (long)(kbase + 64 + kgrow) * 2048 + kcol);
      kr1 = *reinterpret_cast<const uint4*>(Kg + (long)(kbase + 96 + kgrow) * 2048 + kcol);
    }
    // V fragments straight from global
    bf16x8 vf[4][2];
#pragma unroll
    for (int db = 0; db < 4; ++db)
#pragma unroll
      for (int ks = 0; ks < 2; ++ks)
        vf[db][ks] = *reinterpret_cast<const bf16x8*>(Vrow + (size_t)db * 16 * 4096 + kbase + ks * 32);

    // QK^T: per 32-k group: rows {fr, 16+fr}, contraction d=64 in 2 halves
    f32x4 s1[2], s2[2];
#pragma unroll
    for (int ks = 0; ks < 2; ++ks) {
      const unsigned short* ra = &Kb[(ks * 32 + fr) * KSTR];
      const unsigned short* rc = &Kb[(ks * 32 + 16 + fr) * KSTR];
      f32x4 t1 = z4, t2 = z4;
      t1 = __builtin_amdgcn_mfma_f32_16x16x32_bf16(*reinterpret_cast<const bf16x8*>(ra + g * 8), qb0, t1, 0, 0, 0);
      t1 = __builtin_amdgcn_mfma_f32_16x16x32_bf16(*reinterpret_cast<const bf16x8*>(ra + 32 + g * 8), qb1, t1, 0, 0, 0);
      t2 = __builtin_amdgcn_mfma_f32_16x16x32_bf16(*reinterpret_cast<const bf16x8*>(rc + g * 8), qb0, t2, 0, 0, 0);
      t2 = __builtin_amdgcn_mfma_f32_16x16x32_bf16(*reinterpret_cast<const bf16x8*>(rc + 32 + g * 8), qb1, t2, 0, 0, 0);
      s1[ks] = t1; s2[ks] = t2;
    }

    // lane's 16 raw scores: k = kbase + ks*32 + 8g + {j | 4+j}
    float sc[16];
    if (kt + 1 < nkt) {  // fully causal-visible tile: no mask
#pragma unroll
      for (int ks = 0; ks < 2; ++ks)
#pragma unroll
        for (int j = 0; j < 4; ++j) {
          sc[ks * 8 + j] = s1[ks][j];
          sc[ks * 8 + 4 + j] = s2[ks][j];
        }
    } else {
      const int kb8 = kbase + 8 * g;
#pragma unroll
      for (int ks = 0; ks < 2; ++ks)
#pragma unroll
        for (int j = 0; j < 4; ++j) {
          sc[ks * 8 + j]     = (kb8 + ks * 32 + j     <= qg) ? s1[ks][j] : -1e30f;
          sc[ks * 8 + 4 + j] = (kb8 + ks * 32 + 4 + j <= qg) ? s2[ks][j] : -1e30f;
        }
    }
    // max via max3 tree
    const float t0 = fmaxf(fmaxf(sc[0], sc[1]), sc[2]);
    const float t1 = fmaxf(fmaxf(sc[3], sc[4]), sc[5]);
    const float t2 = fmaxf(fmaxf(sc[6], sc[7]), sc[8]);
    const float t3 = fmaxf(fmaxf(sc[9], sc[10]), sc[11]);
    const float t4 = fmaxf(fmaxf(sc[12], sc[13]), sc[14]);
    float tmax = fmaxf(fmaxf(fmaxf(t0, t1), t2), fmaxf(fmaxf(t3, t4), sc[15]));
    tmax = fmaxf(tmax, __shfl_xor(tmax, 16));
    tmax = fmaxf(tmax, __shfl_xor(tmax, 32));
    if (__any(tmax > mrun)) {                    // T13 exact: skip when alpha==1
      const float mnew = fmaxf(mrun, tmax);
      const float alpha = exp2f((mrun - mnew) * C2);
#pragma unroll
      for (int db = 0; db < 4; ++db)
#pragma unroll
        for (int r = 0; r < 4; ++r) acc[db][r] *= alpha;
      lrun *= alpha;
      mrun = mnew;
    }
    const float m2 = mrun * C2;
    bf16x8 pbv[2];
    float psum = 0.f;
#pragma unroll
    for (int ks = 0; ks < 2; ++ks)
#pragma unroll
      for (int j = 0; j < 8; ++j) {
        const float p = exp2f(fmaf(sc[ks * 8 + j], C2, -m2));
        psum += p;
        pbv[ks][j] = (__bf16)p;                  // packs v_cvt_pk_bf16_f32
      }
    psum += __shfl_xor(psum, 16);
    psum += __shfl_xor(psum, 32);
    lrun += psum;

    // PV: acc[db] += V^T-frag * P'-frag
#pragma unroll
    for (int db = 0; db < 4; ++db) {
      acc[db] = __builtin_amdgcn_mfma_f32_16x16x32_bf16(vf[db][0], pbv[0], acc[db], 0, 0, 0);
      acc[db] = __builtin_amdgcn_mfma_f32_16x16x32_bf16(vf[db][1], pbv[1], acc[db], 0, 0, 0);
    }
  }

  // partial store: unnormalized acc (bf16) + (m,l) per q-row
  const long grow = rowb + qbase + fr;
  unsigned short* arow = Apart + ((size_t)sp * BT_ROWS + grow) * DM + hoff;
#pragma unroll
  for (int db = 0; db < 4; ++db) {
    uint2 pk;
    pk.x = (unsigned int)f2bf(acc[db][0]) | ((unsigned int)f2bf(acc[db][1]) << 16);
    pk.y = (unsigned int)f2bf(acc[db][2]) | ((unsigned int)f2bf(acc[db][3]) << 16);
    *reinterpret_cast<uint2*>(arow + db * 16 + g * 4) = pk;
  }
  if (g == 0) ML[((size_t)sp * BT_ROWS + grow) * 16 + h] = make_float2(mrun, lrun);
}

// ---------- combine the 2 K-split partials ----------
__global__ void attn_combine(const unsigned short* __restrict__ Apart,
                             const float2* __restrict__ ML,
                             unsigned short* __restrict__ O) {
  const float C2 = 0.18033688011112042f;
  const int i = blockIdx.x * 256 + threadIdx.x;  // over 4096*16*8
  if (i >= BT_ROWS * 128) return;
  const int d8 = i & 7, h = (i >> 3) & 15, r = i >> 7;
  const float2 ml0 = ML[(size_t)r * 16 + h];
  const float2 ml1 = ML[(size_t)(BT_ROWS + r) * 16 + h];
  const float m = fmaxf(ml0.x, ml1.x);
  const float e0 = exp2f((ml0.x - m) * C2);
  const float e1 = exp2f((ml1.x - m) * C2);
  const float inv = 1.f / (ml0.y * e0 + ml1.y * e1);
  const float f0 = e0 * inv, f1 = e1 * inv;
  const size_t off = (size_t)r * DM + h * 64 + d8 * 8;
  const uint4 a0 = *reinterpret_cast<const uint4*>(Apart + off);
  const uint4 a1 = *reinterpret_cast<const uint4*>(Apart + (size_t)BT_ROWS * DM + off);
  const unsigned int u0[4] = {a0.x, a0.y, a0.z, a0.w};
  const unsigned int u1[4] = {a1.x, a1.y, a1.z, a1.w};
  unsigned int ov[4];
#pragma unroll
  for (int w = 0; w < 4; ++w) {
    const float lo = bf2f(u0[w] & 0xffffu) * f0 + bf2f(u1[w] & 0xffffu) * f1;
    const float hi = bf2f(u0[w] >> 16) * f0 + bf2f(u1[w] >> 16) * f1;
    ov[w] = (unsigned int)f2bf(lo) | ((unsigned int)f2bf(hi) << 16);
  }
  *reinterpret_cast<uint4*>(O + off) = make_uint4(ov[0], ov[1], ov[2], ov[3]);
}

// ---------- workspace layout (lifetime-reused, ~103 MB) ----------
static constexpr size_t OFF_WQKV = 0;          // [3072,1024] bf16
static constexpr size_t OFF_WO   = 6291456;    // [1024,1024] bf16
static constexpr size_t OFF_W13  = 8388608;    // [5632,1024] bf16 interleaved
static constexpr size_t OFF_W2   = 19922944;   // [1024,2816] bf16
static constexpr size_t OFF_H    = 25690112;   // [4096,1024] bf16
static constexpr size_t OFF_X2   = 34078720;   // [4096,1024] f32
static constexpr size_t OFF_CT   = 50855936;   // [4096,32] f32
static constexpr size_t OFF_ST   = 51380224;   // [4096,32] f32
static constexpr size_t OFF_QK   = 51904512;   // [4096,2048] bf16 (later: S [4096,2816])
static constexpr size_t OFF_VT   = 68681728;   // [1024,(h,d)][4096 (b,t)] bf16, 8MB
static constexpr size_t OFF_HO   = 77070336;   // [4096,1024] bf16
static constexpr size_t OFF_AP   = 85458944;   // [2][4096,1024] bf16 partials, 16MB
static constexpr size_t OFF_ML   = 102236160;  // [2][4096][16] float2, 1MB

extern "C" void kernel_launch(void* const* d_in, const int* in_sizes, int n_in,
                              void* d_out, int out_size, void* d_ws, size_t ws_size,
                              hipStream_t stream) {
  const float* x  = (const float*)d_in[0];
  const int* tpos = (const int*)d_in[1];
  const float* WQ = (const float*)d_in[2];
  const float* WK = (const float*)d_in[3];
  const float* WV = (const float*)d_in[4];
  const float* WO = (const float*)d_in[5];
  const float* W1 = (const float*)d_in[6];
  const float* W2 = (const float*)d_in[7];
  const float* W3 = (const float*)d_in[8];
  const float* g1 = (const float*)d_in[9];
  const float* g2 = (const float*)d_in[10];
  float* out = (float*)d_out;

  char* ws = (char*)d_ws;
  unsigned short* Wqkv = (unsigned short*)(ws + OFF_WQKV);
  unsigned short* Wo   = (unsigned short*)(ws + OFF_WO);
  unsigned short* W13i = (unsigned short*)(ws + OFF_W13);
  unsigned short* W2p  = (unsigned short*)(ws + OFF_W2);
  unsigned short* hbuf = (unsigned short*)(ws + OFF_H);
  float* x2            = (float*)(ws + OFF_X2);
  float* ct            = (float*)(ws + OFF_CT);
  float* st            = (float*)(ws + OFF_ST);
  unsigned short* QKb  = (unsigned short*)(ws + OFF_QK);
  unsigned short* Sbuf = (unsigned short*)(ws + OFF_QK);   // reuse after attn
  unsigned short* Vtb  = (unsigned short*)(ws + OFF_VT);
  unsigned short* Ho   = (unsigned short*)(ws + OFF_HO);
  unsigned short* Ap   = (unsigned short*)(ws + OFF_AP);
  float2* ML           = (float2*)(ws + OFF_ML);

  // all weight converts + trig in one launch
  prep_kernel<<<(int)((PREP_TOTAL + 255) / 256), 256, 0, stream>>>(
      WQ, WK, WV, WO, W1, W3, W2, tpos, Wqkv, Wo, W13i, W2p, ct, st);

  // attention sublayer
  rmsnorm_kernel<<<BT_ROWS, 256, 0, stream>>>(x, g1, hbuf);
  gemm_bt<0, 128><<<dim3(16, 32), 256, 0, stream>>>(hbuf, Wqkv, QKb, nullptr, BT_ROWS, 2048, 1024, 2048);
  // Vt = Wv * h^T : coalesced V^T, BN=64 -> 512 blocks (2/CU)
  gemm_bt<0, 64><<<dim3(64, 8), 256, 0, stream>>>(Wqkv + 2048 * 1024, hbuf, Vtb, nullptr, 1024, BT_ROWS, 1024, BT_ROWS);
  rope_kernel<<<(BT_ROWS * 512) / 256, 256, 0, stream>>>(QKb, ct, st);
  attn_kernel<<<dim3(32, 64), 256, 0, stream>>>(QKb, Vtb, Ap, ML);
  attn_combine<<<(BT_ROWS * 128 + 255) / 256, 256, 0, stream>>>(Ap, ML, Ho);
  gemm_bt<1, 64><<<dim3(16, 32), 256, 0, stream>>>(Ho, Wo, x2, x, BT_ROWS, 1024, 1024, 1024);

  // FFN sublayer (SwiGLU fused into W13 epilogue)
  rmsnorm_kernel<<<BT_ROWS, 256, 0, stream>>>(x2, g2, hbuf);
  gemm_bt<3, 128><<<dim3(44, 32), 256, 0, stream>>>(hbuf, W13i, Sbuf, nullptr, BT_ROWS, 2 * DFFP, 1024, DFFP);
  gemm_bt<1, 64><<<dim3(16, 32), 256, 0, stream>>>(Sbuf, W2p, out, x2, BT_ROWS, 1024, DFFP, 1024);
}

// Round 9
// 274.564 us; speedup vs baseline: 1.3169x; 1.0710x over previous
//
#include <hip/hip_runtime.h>
#include <cstdint>

// ---------- sizes ----------
#define BT_ROWS 4096      // B*T
#define DM      1024
#define DFF     2730
#define DFFP    2816      // padded to /128
#define TSEQ    2048

typedef float  f32x4  __attribute__((ext_vector_type(4)));
typedef __bf16 bf16x8 __attribute__((ext_vector_type(8)));

typedef __attribute__((address_space(1))) const unsigned int as1_uint;
typedef __attribute__((address_space(3))) unsigned int       as3_uint;

__device__ __forceinline__ unsigned short f2bf(float f) {
  union { float f; unsigned int u; } v; v.f = f;
  unsigned int u = v.u;
  return (unsigned short)((u + 0x7fffu + ((u >> 16) & 1u)) >> 16);  // RNE
}
__device__ __forceinline__ float bf2f(unsigned int b) {
  union { unsigned int u; float f; } v; v.u = b << 16;
  return v.f;
}

__device__ __forceinline__ void async_cp16(const void* g, void* l) {
  // 16B-wide global->LDS DMA; LDS dest is wave-uniform base + lane*16
  __builtin_amdgcn_global_load_lds((as1_uint*)(uintptr_t)g, (as3_uint*)(uintptr_t)l, 16, 0, 0);
}

// ---------- fused prep: all weight converts (+pad/interleave) + RoPE trig ----------
// Segment sizes are multiples of 256 -> no intra-block divergence.
__global__ void prep_kernel(const float* __restrict__ WQ, const float* __restrict__ WK,
                            const float* __restrict__ WV, const float* __restrict__ WOp,
                            const float* __restrict__ W1, const float* __restrict__ W3,
                            const float* __restrict__ W2, const int* __restrict__ pos,
                            unsigned short* __restrict__ Wqkv, unsigned short* __restrict__ Wo,
                            unsigned short* __restrict__ W13i, unsigned short* __restrict__ W2p,
                            float* __restrict__ ct, float* __restrict__ st) {
  long idx = (long)blockIdx.x * 256 + threadIdx.x;
  if (idx < 4194304) {                       // 4 square 1024x1024 mats
    const int j = (int)(idx >> 20);
    const long t = idx & 1048575;
    const float* s = (j == 0) ? WQ : (j == 1) ? WK : (j == 2) ? WV : WOp;
    unsigned short* d = (j < 3) ? (Wqkv + (size_t)j * 1048576) : Wo;
    d[t] = f2bf(s[t]);
    return;
  }
  idx -= 4194304;
  if (idx < 2L * DFFP * 1024) {              // W1/W3 row-interleaved + pad
    const int half = (int)(idx / (DFFP * 1024));
    const long t = idx % (DFFP * 1024);
    const int r = (int)(t >> 10), c = (int)(t & 1023);
    const float v = (r < DFF) ? (half ? W3 : W1)[(long)r * 1024 + c] : 0.f;
    W13i[((long)2 * r + half) * 1024 + c] = f2bf(v);
    return;
  }
  idx -= 2L * DFFP * 1024;
  if (idx < 1024L * DFFP) {                  // W2 col-padded
    const int c = (int)(idx % DFFP), r = (int)(idx / DFFP);
    const float v = (c < DFF) ? W2[(long)r * DFF + c] : 0.f;
    W2p[idx] = f2bf(v);
    return;
  }
  idx -= 1024L * DFFP;
  if (idx < BT_ROWS * 32) {                  // RoPE cos/sin table
    const int r = (int)(idx >> 5), i = (int)(idx & 31);
    const float f = powf(10000.f, -(float)(2 * i) * (1.f / 64.f));
    float sv, cv;
    sincosf((float)pos[r] * f, &sv, &cv);
    ct[idx] = cv; st[idx] = sv;
  }
}
#define PREP_TOTAL (4194304L + 2L * DFFP * 1024 + 1024L * DFFP + BT_ROWS * 32)

// ---------- RMSNorm (fp32 in -> bf16 out), one block per row ----------
__global__ void rmsnorm_kernel(const float* __restrict__ x, const float* __restrict__ g,
                               unsigned short* __restrict__ out) {
  const int row = blockIdx.x, tid = threadIdx.x;
  const float4 xv = reinterpret_cast<const float4*>(x + (long)row * DM)[tid];
  float ss = xv.x * xv.x + xv.y * xv.y + xv.z * xv.z + xv.w * xv.w;
#pragma unroll
  for (int o = 32; o > 0; o >>= 1) ss += __shfl_xor(ss, o);
  __shared__ float wsum[4];
  if ((tid & 63) == 0) wsum[tid >> 6] = ss;
  __syncthreads();
  const float inv = rsqrtf((wsum[0] + wsum[1] + wsum[2] + wsum[3]) * (1.f / DM) + 1e-5f);
  const float4 gv = reinterpret_cast<const float4*>(g)[tid];
  ushort4 o4;
  o4.x = f2bf(xv.x * inv * gv.x);
  o4.y = f2bf(xv.y * inv * gv.y);
  o4.z = f2bf(xv.z * inv * gv.z);
  o4.w = f2bf(xv.w * inv * gv.w);
  reinterpret_cast<ushort4*>(out + (long)row * DM)[tid] = o4;
}

// ---------- RoPE applied in-place to Q,K halves of QK buf (bf16, ld 2048) ----------
__global__ void rope_kernel(unsigned short* __restrict__ QK,
                            const float* __restrict__ ct, const float* __restrict__ st) {
  int idx = blockIdx.x * 256 + threadIdx.x;  // over 4096*512 (row, head*pair)
  if (idx >= BT_ROWS * 512) return;
  int r = idx >> 9, p = idx & 511;
  int h = p >> 5, i = p & 31;
  float c = ct[r * 32 + i], s = st[r * 32 + i];
  unsigned int* base = reinterpret_cast<unsigned int*>(QK + (long)r * 2048 + h * 64 + 2 * i);
  unsigned int q01 = base[0];
  float x0 = bf2f(q01 & 0xffffu), x1 = bf2f(q01 >> 16);
  base[0] = (unsigned int)f2bf(c * x0 - s * x1) | ((unsigned int)f2bf(s * x0 + c * x1) << 16);
  unsigned int k01 = base[512];  // +1024 shorts = K block
  float y0 = bf2f(k01 & 0xffffu), y1 = bf2f(k01 >> 16);
  base[512] = (unsigned int)f2bf(c * y0 - s * y1) | ((unsigned int)f2bf(s * y0 + c * y1) << 16);
}

// ---------- GEMM: C[M,N] = A[M,K] * B[N,K]^T  (bf16 in, fp32 acc) ----------
// 128xBN tile, BK=64, XOR-swizzled LDS (pre-swizzled global src).
// 2-PHASE double-buffer (T3 minimal): issue next tile's global_load_lds
// BEFORE computing the current tile; one barrier per K-step drains late.
// EPI 0: bf16 store; EPI 1: fp32 acc+resid; EPI 3: fused SwiGLU
template <int EPI, int BN>
__global__ __launch_bounds__(256) void gemm_bt(
    const unsigned short* __restrict__ A, const unsigned short* __restrict__ B,
    void* __restrict__ C, const float* __restrict__ resid,
    int M, int N, int K, int ldc) {
  constexpr int WNF = BN / 32;              // B-frags per wave (4 or 2)
  __shared__ unsigned short As[2][128 * 64];
  __shared__ unsigned short Bs[2][BN * 64];
  const int tid = threadIdx.x;
  const int wid = tid >> 6;
  const int lane = tid & 63;
  const long rowBase = (long)blockIdx.y * 128;
  const long colBase = (long)blockIdx.x * BN;
  const int wm = (wid >> 1) * 64;
  const int wn = (wid & 1) * (BN / 2);
  const int srow = wid * 8 + (lane >> 3);   // staging row within 32-row group
  const int sc   = lane & 7;                // staging 16B chunk
  const int cs   = (sc ^ (srow & 7)) * 8;   // pre-swizzled source chunk (elems)
  const int fr = lane & 15;                 // fragment row
  const int fg = lane >> 4;                 // fragment k-group

  const f32x4 z4 = {0.f, 0.f, 0.f, 0.f};
  f32x4 acc[4][WNF];
#pragma unroll
  for (int m = 0; m < 4; ++m)
#pragma unroll
    for (int n = 0; n < WNF; ++n) acc[m][n] = z4;

  auto stage = [&](int buf, int kt) {
    const long kOff = (long)kt * 64 + cs;
    char* AsB = (char*)As[buf];
    char* BsB = (char*)Bs[buf];
#pragma unroll
    for (int i = 0; i < 4; ++i)
      async_cp16(A + (rowBase + i * 32 + srow) * K + kOff, AsB + i * 4096 + wid * 1024);
#pragma unroll
    for (int i = 0; i < WNF; ++i)
      async_cp16(B + (colBase + i * 32 + srow) * K + kOff, BsB + i * 4096 + wid * 1024);
  };

  const int nkt = K >> 6;
  stage(0, 0);
  __syncthreads();                          // drain vmcnt(0): buf0 ready
  for (int kt = 0; kt < nkt; ++kt) {
    if (kt + 1 < nkt) stage((kt + 1) & 1, kt + 1);   // issue-early (in flight)
    const char* AsB = (const char*)As[kt & 1];
    const char* BsB = (const char*)Bs[kt & 1];
#pragma unroll
    for (int kk = 0; kk < 2; ++kk) {
      bf16x8 af[4], bfr[WNF];
#pragma unroll
      for (int m = 0; m < 4; ++m)
        af[m] = *(const bf16x8*)(AsB + (wm + m * 16 + fr) * 128 + (((kk * 4 + fg) ^ (fr & 7)) * 16));
#pragma unroll
      for (int n = 0; n < WNF; ++n)
        bfr[n] = *(const bf16x8*)(BsB + (wn + n * 16 + fr) * 128 + (((kk * 4 + fg) ^ (fr & 7)) * 16));
#pragma unroll
      for (int m = 0; m < 4; ++m)
#pragma unroll
        for (int n = 0; n < WNF; ++n)
          acc[m][n] = __builtin_amdgcn_mfma_f32_16x16x32_bf16(af[m], bfr[n], acc[m][n], 0, 0, 0);
    }
    __syncthreads();                        // drain-late: next buf ready, LDS safe
  }

  const int erow = fg * 4;  // C: col = lane&15, row = (lane>>4)*4 + reg
  if (EPI == 0) {
    unsigned short* Cp = (unsigned short*)C;
#pragma unroll
    for (int m = 0; m < 4; ++m) {
      const long r0 = rowBase + wm + m * 16 + erow;
#pragma unroll
      for (int n = 0; n < WNF; ++n) {
        const long col = colBase + wn + n * 16 + fr;
#pragma unroll
        for (int r = 0; r < 4; ++r) Cp[(r0 + r) * ldc + col] = f2bf(acc[m][n][r]);
      }
    }
  } else if (EPI == 1) {
    float* Cf = (float*)C;
#pragma unroll
    for (int m = 0; m < 4; ++m) {
      const long r0 = rowBase + wm + m * 16 + erow;
#pragma unroll
      for (int n = 0; n < WNF; ++n) {
        const long col = colBase + wn + n * 16 + fr;
#pragma unroll
        for (int r = 0; r < 4; ++r) {
          const long o = (r0 + r) * ldc + col;
          Cf[o] = acc[m][n][r] + resid[o];
        }
      }
    }
  } else {
    // fused SwiGLU: even col = u (W1 row), odd col = g (W3 row); out col/2
    unsigned short* Cp = (unsigned short*)C;
    const int even = !(fr & 1);
#pragma unroll
    for (int m = 0; m < 4; ++m) {
      const long r0 = rowBase + wm + m * 16 + erow;
#pragma unroll
      for (int n = 0; n < WNF; ++n) {
        const long col = colBase + wn + n * 16 + fr;
        const long fcol = col >> 1;
#pragma unroll
        for (int r = 0; r < 4; ++r) {
          const float own = acc[m][n][r];
          const float oth = __shfl_xor(own, 1);
          if (even) {
            const float s = own * oth / (1.f + __expf(-own));
            Cp[(r0 + r) * ldc + fcol] = f2bf(s);
          }
        }
      }
    }
  }
}

// ---------- flash attention, causal, 16 heads x d_k=64 (measured-best form) ----------
// S' = K*Q^T (swapped) with permuted K staging so P' lands in the PV B-frag
// layout. Block = 4 waves x 16 q-rows. KVBLK=64, K double-buffered in LDS
// (1 barrier/tile), V^T read directly from global (L2/L3-resident).
#define KSTR 72
__global__ __launch_bounds__(256) void attn_kernel(
    const unsigned short* __restrict__ QK, const unsigned short* __restrict__ Vt,
    unsigned short* __restrict__ O) {
  __shared__ unsigned short Ks[2][64 * KSTR];
  const int bh = blockIdx.x;
  const int b = bh >> 4, h = bh & 15;
  const int tid = threadIdx.x;
  const int wid = tid >> 6, lane = tid & 63;
  const int qblk = 31 - blockIdx.y;              // longest-first dispatch
  const int qbase = qblk * 64 + wid * 16;
  const int fr = lane & 15, g = lane >> 4;
  const long rowb = (long)b * TSEQ;
  const int hoff = h * 64;
  const float C2 = 0.18033688011112042f;         // 0.125 * log2(e)

  // K staging map (per 32-row group, permuted rows)
  const int ki = tid >> 3;                       // 0..31
  const int kcol = (tid & 7) * 8;
  const int kgrow = 8 * ((ki & 15) >> 2) + (ki & 3) + ((ki >> 4) << 2);

  const unsigned short* qrow = QK + (rowb + qbase + fr) * 2048 + hoff + g * 8;
  const bf16x8 qb0 = *reinterpret_cast<const bf16x8*>(qrow);
  const bf16x8 qb1 = *reinterpret_cast<const bf16x8*>(qrow + 32);

  const unsigned short* Kg = QK + rowb * 2048 + 1024 + hoff;
  // V^T: Vt[(h*64+d)][b*2048 + t]
  const unsigned short* Vrow = Vt + (long)(hoff + fr) * 4096 + rowb + g * 8;

  const f32x4 z4 = {0.f, 0.f, 0.f, 0.f};
  f32x4 acc[4];
#pragma unroll
  for (int d = 0; d < 4; ++d) acc[d] = z4;
  float mrun = -1e30f, lrun = 0.f;
  const int qg = qbase + fr;
  const int nkt = qblk + 1;

  uint4 kr0 = *reinterpret_cast<const uint4*>(Kg + (long)kgrow * 2048 + kcol);
  uint4 kr1 = *reinterpret_cast<const uint4*>(Kg + (long)(32 + kgrow) * 2048 + kcol);

  for (int kt = 0; kt < nkt; ++kt) {
    unsigned short* Kb = Ks[kt & 1];
    *reinterpret_cast<uint4*>(&Kb[ki * KSTR + kcol]) = kr0;
    *reinterpret_cast<uint4*>(&Kb[(32 + ki) * KSTR + kcol]) = kr1;
    __syncthreads();   // writes visible; prev tile's compute (other buf) done
    const int kbase = kt * 64;
    if (kt + 1 < nkt) {
      kr0 = *reinterpret_cast<const uint4*>(Kg + (long)(kbase + 64 + kgrow) * 2048 + kcol);
      kr1 = *reinterpret_cast<const uint4*>(Kg + (long)(kbase + 96 + kgrow) * 2048 + kcol);
    }
    // V fragments straight from global
    bf16x8 vf[4][2];
#pragma unroll
    for (int db = 0; db < 4; ++db)
#pragma unroll
      for (int ks = 0; ks < 2; ++ks)
        vf[db][ks] = *reinterpret_cast<const bf16x8*>(Vrow + (size_t)db * 16 * 4096 + kbase + ks * 32);

    // QK^T: per 32-k group: rows {fr, 16+fr}, contraction d=64 in 2 halves
    f32x4 s1[2], s2[2];
#pragma unroll
    for (int ks = 0; ks < 2; ++ks) {
      const unsigned short* ra = &Kb[(ks * 32 + fr) * KSTR];
      const unsigned short* rc = &Kb[(ks * 32 + 16 + fr) * KSTR];
      f32x4 t1 = z4, t2 = z4;
      t1 = __builtin_amdgcn_mfma_f32_16x16x32_bf16(*reinterpret_cast<const bf16x8*>(ra + g * 8), qb0, t1, 0, 0, 0);
      t1 = __builtin_amdgcn_mfma_f32_16x16x32_bf16(*reinterpret_cast<const bf16x8*>(ra + 32 + g * 8), qb1, t1, 0, 0, 0);
      t2 = __builtin_amdgcn_mfma_f32_16x16x32_bf16(*reinterpret_cast<const bf16x8*>(rc + g * 8), qb0, t2, 0, 0, 0);
      t2 = __builtin_amdgcn_mfma_f32_16x16x32_bf16(*reinterpret_cast<const bf16x8*>(rc + 32 + g * 8), qb1, t2, 0, 0, 0);
      s1[ks] = t1; s2[ks] = t2;
    }

    // lane's 16 raw scores: k = kbase + ks*32 + 8g + {j | 4+j}
    float sc[16];
    if (kt + 1 < nkt) {  // fully causal-visible tile: no mask
#pragma unroll
      for (int ks = 0; ks < 2; ++ks)
#pragma unroll
        for (int j = 0; j < 4; ++j) {
          sc[ks * 8 + j] = s1[ks][j];
          sc[ks * 8 + 4 + j] = s2[ks][j];
        }
    } else {
      const int kb8 = kbase + 8 * g;
#pragma unroll
      for (int ks = 0; ks < 2; ++ks)
#pragma unroll
        for (int j = 0; j < 4; ++j) {
          sc[ks * 8 + j]     = (kb8 + ks * 32 + j     <= qg) ? s1[ks][j] : -1e30f;
          sc[ks * 8 + 4 + j] = (kb8 + ks * 32 + 4 + j <= qg) ? s2[ks][j] : -1e30f;
        }
    }
    // max via max3 tree
    const float t0 = fmaxf(fmaxf(sc[0], sc[1]), sc[2]);
    const float t1 = fmaxf(fmaxf(sc[3], sc[4]), sc[5]);
    const float t2 = fmaxf(fmaxf(sc[6], sc[7]), sc[8]);
    const float t3 = fmaxf(fmaxf(sc[9], sc[10]), sc[11]);
    const float t4 = fmaxf(fmaxf(sc[12], sc[13]), sc[14]);
    float tmax = fmaxf(fmaxf(fmaxf(t0, t1), t2), fmaxf(fmaxf(t3, t4), sc[15]));
    tmax = fmaxf(tmax, __shfl_xor(tmax, 16));
    tmax = fmaxf(tmax, __shfl_xor(tmax, 32));
    if (__any(tmax > mrun)) {                    // T13 exact: skip when alpha==1
      const float mnew = fmaxf(mrun, tmax);
      const float alpha = exp2f((mrun - mnew) * C2);
#pragma unroll
      for (int db = 0; db < 4; ++db)
#pragma unroll
        for (int r = 0; r < 4; ++r) acc[db][r] *= alpha;
      lrun *= alpha;
      mrun = mnew;
    }
    const float m2 = mrun * C2;
    bf16x8 pbv[2];
    float psum = 0.f;
#pragma unroll
    for (int ks = 0; ks < 2; ++ks)
#pragma unroll
      for (int j = 0; j < 8; ++j) {
        const float p = exp2f(fmaf(sc[ks * 8 + j], C2, -m2));
        psum += p;
        pbv[ks][j] = (__bf16)p;                  // packs v_cvt_pk_bf16_f32
      }
    psum += __shfl_xor(psum, 16);
    psum += __shfl_xor(psum, 32);
    lrun += psum;

    // PV: acc[db] += V^T-frag * P'-frag
#pragma unroll
    for (int db = 0; db < 4; ++db) {
      acc[db] = __builtin_amdgcn_mfma_f32_16x16x32_bf16(vf[db][0], pbv[0], acc[db], 0, 0, 0);
      acc[db] = __builtin_amdgcn_mfma_f32_16x16x32_bf16(vf[db][1], pbv[1], acc[db], 0, 0, 0);
    }
  }

  const float inv = 1.f / lrun;
  unsigned short* orow = O + (rowb + qbase + fr) * DM + hoff;
#pragma unroll
  for (int db = 0; db < 4; ++db) {
    uint2 pk;
    pk.x = (unsigned int)f2bf(acc[db][0] * inv) | ((unsigned int)f2bf(acc[db][1] * inv) << 16);
    pk.y = (unsigned int)f2bf(acc[db][2] * inv) | ((unsigned int)f2bf(acc[db][3] * inv) << 16);
    *reinterpret_cast<uint2*>(orow + db * 16 + g * 4) = pk;
  }
}

// ---------- workspace layout (lifetime-reused) ----------
static constexpr size_t OFF_WQKV = 0;          // [3072,1024] bf16
static constexpr size_t OFF_WO   = 6291456;    // [1024,1024] bf16
static constexpr size_t OFF_W13  = 8388608;    // [5632,1024] bf16 interleaved
static constexpr size_t OFF_W2   = 19922944;   // [1024,2816] bf16
static constexpr size_t OFF_H    = 25690112;   // [4096,1024] bf16
static constexpr size_t OFF_X2   = 34078720;   // [4096,1024] f32
static constexpr size_t OFF_CT   = 50855936;   // [4096,32] f32
static constexpr size_t OFF_ST   = 51380224;   // [4096,32] f32
static constexpr size_t OFF_QK   = 51904512;   // [4096,2048] bf16 (later: S [4096,2816])
static constexpr size_t OFF_VT   = 68681728;   // [1024,(h,d)][4096 (b,t)] bf16, 8MB
static constexpr size_t OFF_HO   = 77070336;   // [4096,1024] bf16

extern "C" void kernel_launch(void* const* d_in, const int* in_sizes, int n_in,
                              void* d_out, int out_size, void* d_ws, size_t ws_size,
                              hipStream_t stream) {
  const float* x  = (const float*)d_in[0];
  const int* tpos = (const int*)d_in[1];
  const float* WQ = (const float*)d_in[2];
  const float* WK = (const float*)d_in[3];
  const float* WV = (const float*)d_in[4];
  const float* WO = (const float*)d_in[5];
  const float* W1 = (const float*)d_in[6];
  const float* W2 = (const float*)d_in[7];
  const float* W3 = (const float*)d_in[8];
  const float* g1 = (const float*)d_in[9];
  const float* g2 = (const float*)d_in[10];
  float* out = (float*)d_out;

  char* ws = (char*)d_ws;
  unsigned short* Wqkv = (unsigned short*)(ws + OFF_WQKV);
  unsigned short* Wo   = (unsigned short*)(ws + OFF_WO);
  unsigned short* W13i = (unsigned short*)(ws + OFF_W13);
  unsigned short* W2p  = (unsigned short*)(ws + OFF_W2);
  unsigned short* hbuf = (unsigned short*)(ws + OFF_H);
  float* x2            = (float*)(ws + OFF_X2);
  float* ct            = (float*)(ws + OFF_CT);
  float* st            = (float*)(ws + OFF_ST);
  unsigned short* QKb  = (unsigned short*)(ws + OFF_QK);
  unsigned short* Sbuf = (unsigned short*)(ws + OFF_QK);   // reuse after attn
  unsigned short* Vtb  = (unsigned short*)(ws + OFF_VT);
  unsigned short* Ho   = (unsigned short*)(ws + OFF_HO);

  // all weight converts + trig in one launch
  prep_kernel<<<(int)((PREP_TOTAL + 255) / 256), 256, 0, stream>>>(
      WQ, WK, WV, WO, W1, W3, W2, tpos, Wqkv, Wo, W13i, W2p, ct, st);

  // attention sublayer
  rmsnorm_kernel<<<BT_ROWS, 256, 0, stream>>>(x, g1, hbuf);
  gemm_bt<0, 128><<<dim3(16, 32), 256, 0, stream>>>(hbuf, Wqkv, QKb, nullptr, BT_ROWS, 2048, 1024, 2048);
  // Vt = Wv * h^T : coalesced V^T, BN=64 -> 512 blocks
  gemm_bt<0, 64><<<dim3(64, 8), 256, 0, stream>>>(Wqkv + 2048 * 1024, hbuf, Vtb, nullptr, 1024, BT_ROWS, 1024, BT_ROWS);
  rope_kernel<<<(BT_ROWS * 512) / 256, 256, 0, stream>>>(QKb, ct, st);
  attn_kernel<<<dim3(32, 32), 256, 0, stream>>>(QKb, Vtb, Ho);
  gemm_bt<1, 64><<<dim3(16, 32), 256, 0, stream>>>(Ho, Wo, x2, x, BT_ROWS, 1024, 1024, 1024);

  // FFN sublayer (SwiGLU fused into W13 epilogue)
  rmsnorm_kernel<<<BT_ROWS, 256, 0, stream>>>(x2, g2, hbuf);
  gemm_bt<3, 128><<<dim3(44, 32), 256, 0, stream>>>(hbuf, W13i, Sbuf, nullptr, BT_ROWS, 2 * DFFP, 1024, DFFP);
  gemm_bt<1, 64><<<dim3(16, 32), 256, 0, stream>>>(Sbuf, W2p, out, x2, BT_ROWS, 1024, DFFP, 1024);
}